// Round 4
// baseline (609.583 us; speedup 1.0000x reference)
//
#include <hip/hip_runtime.h>
#include <hip/hip_bf16.h>
#include <hip/hip_fp16.h>

typedef __attribute__((ext_vector_type(8))) _Float16 f16x8;
typedef __attribute__((ext_vector_type(4))) _Float16 f16x4;
typedef __attribute__((ext_vector_type(4))) float f32x4;

static __device__ __forceinline__ void st(float* p, float v)  { *p = v; }
static __device__ __forceinline__ void st(__half* p, float v) { *p = __float2half(v); }

// fp32 -> f16 hi/lo split (residual <= 2^-22 relative)
static __device__ __forceinline__ void splitf16(float v, __half& hi, __half& lo) {
    hi = __float2half(v);
    lo = __float2half(v - __half2float(hi));
}

// vectorized f16 row loaders (CHUNK consecutive channels per lane)
static __device__ __forceinline__ void ldrow4(const __half* p, float* f) {
    const __half2* q = reinterpret_cast<const __half2*>(p);
    float2 a = __half22float2(q[0]), b = __half22float2(q[1]);
    f[0] = a.x; f[1] = a.y; f[2] = b.x; f[3] = b.y;
}
template <int CHUNK>
static __device__ __forceinline__ void ldrow(const __half* p, float* f) {
    if constexpr (CHUNK == 4) ldrow4(p, f); else f[0] = __half2float(*p);
}

// ---------------- CSR build ----------------
__global__ void k_init(int* deg, int N) {
    int i = blockIdx.x * blockDim.x + threadIdx.x;
    if (i < N) deg[i] = 1;              // self-loop
}

__global__ void k_hist(const int* __restrict__ ei, int* deg, int E) {
    int e = blockIdx.x * blockDim.x + threadIdx.x;
    if (e < E) atomicAdd(&deg[ei[E + e]], 1);
}

__global__ void k_scan1(const int* __restrict__ deg, int* __restrict__ offs,
                        int* __restrict__ bsum, int N) {
    __shared__ int sh[256];
    int i = blockIdx.x * 256 + threadIdx.x;
    int v = (i < N) ? deg[i] : 0;
    sh[threadIdx.x] = v;
    __syncthreads();
#pragma unroll
    for (int off = 1; off < 256; off <<= 1) {
        int t = (threadIdx.x >= off) ? sh[threadIdx.x - off] : 0;
        __syncthreads();
        sh[threadIdx.x] += t;
        __syncthreads();
    }
    if (i < N) offs[i] = sh[threadIdx.x] - v;
    if (threadIdx.x == 255) bsum[blockIdx.x] = sh[255];
}

__global__ void k_scan2(int* __restrict__ bsum, int nb) {   // nb <= 256, single block
    __shared__ int sh[256];
    int v = (threadIdx.x < nb) ? bsum[threadIdx.x] : 0;
    sh[threadIdx.x] = v;
    __syncthreads();
#pragma unroll
    for (int off = 1; off < 256; off <<= 1) {
        int t = (threadIdx.x >= off) ? sh[threadIdx.x - off] : 0;
        __syncthreads();
        sh[threadIdx.x] += t;
        __syncthreads();
    }
    if (threadIdx.x < nb) bsum[threadIdx.x] = sh[threadIdx.x] - v;
    if (threadIdx.x == 255) bsum[nb] = sh[255];
}

__global__ void k_scan3(int* __restrict__ offs, int* __restrict__ cursor,
                        const int* __restrict__ bsum, int N, int nb) {
    int i = blockIdx.x * 256 + threadIdx.x;
    if (i < N) {
        int v = offs[i] + bsum[blockIdx.x];
        offs[i] = v;
        cursor[i] = v;
    }
    if (i == 0) offs[N] = bsum[nb];
}

__global__ void k_scatter(const int* __restrict__ ei, int* cursor, int* csr, int E) {
    int e = blockIdx.x * blockDim.x + threadIdx.x;
    if (e < E) {
        int d = ei[E + e];
        int p = atomicAdd(&cursor[d], 1);
        csr[p] = ei[e];
    }
}

__global__ void k_scatter_loops(int* cursor, int* csr, int N) {
    int i = blockIdx.x * blockDim.x + threadIdx.x;
    if (i < N) { int p = atomicAdd(&cursor[i], 1); csr[p] = i; }
}

// ---------------- pre-split kernels (f16 basis) ----------------
// W [K x M] fp32 -> transposed f16 hi/lo [M x K]
__global__ void k_wsplit(const float* __restrict__ W, __half* __restrict__ Wth,
                         __half* __restrict__ Wtl, int K, int M) {
    int idx = blockIdx.x * 256 + threadIdx.x;
    if (idx < K * M) {
        int k = idx / M, n = idx - k * M;
        __half h, l;
        splitf16(W[idx], h, l);
        Wth[(size_t)n * K + k] = h;
        Wtl[(size_t)n * K + k] = l;
    }
}

// x fp32 -> f16 hi/lo (row-major), vectorized: float4 in, ushort4 out
__global__ void k_xsplit(const float* __restrict__ x, __half* __restrict__ xh,
                         __half* __restrict__ xl, long n4) {
    long i = (long)blockIdx.x * 256 + threadIdx.x;   // in units of 4 floats
    if (i < n4) {
        float4 v = *reinterpret_cast<const float4*>(x + i * 4);
        __half h0, h1, h2, h3, l0, l1, l2, l3;
        splitf16(v.x, h0, l0);
        splitf16(v.y, h1, l1);
        splitf16(v.z, h2, l2);
        splitf16(v.w, h3, l3);
        ushort4 hv = { __half_as_ushort(h0), __half_as_ushort(h1),
                       __half_as_ushort(h2), __half_as_ushort(h3) };
        ushort4 lv = { __half_as_ushort(l0), __half_as_ushort(l1),
                       __half_as_ushort(l2), __half_as_ushort(l3) };
        *reinterpret_cast<ushort4*>(xh + i * 4) = hv;
        *reinterpret_cast<ushort4*>(xl + i * 4) = lv;
    }
}

// ---------------- f16-split MFMA GEMMs ----------------
// Layer 1 (3-term): C = (Ah+Al) @ (Wh+Wl) ~= AhWh + AhWl + AlWh
// BM=128, BN=64, BK=32; 4 waves 2x2; LDA=40 halves (80B, 16B-aligned).
__global__ __launch_bounds__(256) void k_gemm3(const __half* __restrict__ Ah, const __half* __restrict__ Al,
                                               const __half* __restrict__ Wth, const __half* __restrict__ Wtl,
                                               __half* __restrict__ C, int nrows, int K, int M) {
    constexpr int LDA = 40;
    __shared__ __half AH[128 * LDA];
    __shared__ __half AL[128 * LDA];
    __shared__ __half BH[64 * LDA];
    __shared__ __half BL[64 * LDA];

    int tid  = threadIdx.x;
    int lane = tid & 63;
    int wave = tid >> 6;
    int wr = wave & 1, wc = wave >> 1;
    int quad = lane >> 4, r = lane & 15;
    int r0 = blockIdx.x * 128, c0 = blockIdx.y * 64;

    f32x4 acc[4][2];
#pragma unroll
    for (int i = 0; i < 4; ++i)
#pragma unroll
        for (int j = 0; j < 2; ++j) acc[i][j] = (f32x4){0.f, 0.f, 0.f, 0.f};

    for (int kc = 0; kc < K; kc += 32) {
#pragma unroll
        for (int it = 0; it < 2; ++it) {
            int row  = (tid >> 2) + it * 64;
            int kseg = (tid & 3) * 8;
            int gr = r0 + row;
            f16x8 vh = (f16x8)(_Float16)0, vl = (f16x8)(_Float16)0;
            if (gr < nrows) {
                vh = *reinterpret_cast<const f16x8*>(Ah + (size_t)gr * K + kc + kseg);
                vl = *reinterpret_cast<const f16x8*>(Al + (size_t)gr * K + kc + kseg);
            }
            *reinterpret_cast<f16x8*>(&AH[row * LDA + kseg]) = vh;
            *reinterpret_cast<f16x8*>(&AL[row * LDA + kseg]) = vl;
        }
        {
            int n    = tid >> 2;
            int kseg = (tid & 3) * 8;
            *reinterpret_cast<f16x8*>(&BH[n * LDA + kseg]) =
                *reinterpret_cast<const f16x8*>(Wth + (size_t)(c0 + n) * K + kc + kseg);
            *reinterpret_cast<f16x8*>(&BL[n * LDA + kseg]) =
                *reinterpret_cast<const f16x8*>(Wtl + (size_t)(c0 + n) * K + kc + kseg);
        }
        __syncthreads();
        int k0 = quad * 8;
        f16x8 ah[4], al[4], bh[2], bl[2];
#pragma unroll
        for (int tr = 0; tr < 4; ++tr) {
            int row = wr * 64 + tr * 16 + r;
            ah[tr] = *reinterpret_cast<const f16x8*>(&AH[row * LDA + k0]);
            al[tr] = *reinterpret_cast<const f16x8*>(&AL[row * LDA + k0]);
        }
#pragma unroll
        for (int tc = 0; tc < 2; ++tc) {
            int col = wc * 32 + tc * 16 + r;
            bh[tc] = *reinterpret_cast<const f16x8*>(&BH[col * LDA + k0]);
            bl[tc] = *reinterpret_cast<const f16x8*>(&BL[col * LDA + k0]);
        }
#pragma unroll
        for (int tr = 0; tr < 4; ++tr)
#pragma unroll
            for (int tc = 0; tc < 2; ++tc) {
                acc[tr][tc] = __builtin_amdgcn_mfma_f32_16x16x32_f16(ah[tr], bh[tc], acc[tr][tc], 0, 0, 0);
                acc[tr][tc] = __builtin_amdgcn_mfma_f32_16x16x32_f16(ah[tr], bl[tc], acc[tr][tc], 0, 0, 0);
                acc[tr][tc] = __builtin_amdgcn_mfma_f32_16x16x32_f16(al[tr], bh[tc], acc[tr][tc], 0, 0, 0);
            }
        __syncthreads();
    }
#pragma unroll
    for (int tr = 0; tr < 4; ++tr)
#pragma unroll
        for (int tc = 0; tc < 2; ++tc) {
            int col = c0 + wc * 32 + tc * 16 + r;
#pragma unroll
            for (int i = 0; i < 4; ++i) {
                int row = r0 + wr * 64 + tr * 16 + quad * 4 + i;
                if (row < nrows) C[(size_t)row * M + col] = __float2half(acc[tr][tc][i]);
            }
        }
}

// Layers 2/3 (2-term): A is exact f16 -> C = A @ (Wh+Wl). LDS ~20.5 KB.
__global__ __launch_bounds__(256) void k_gemm2(const __half* __restrict__ A,
                                               const __half* __restrict__ Wth, const __half* __restrict__ Wtl,
                                               __half* __restrict__ C, int nrows, int K, int M) {
    constexpr int LDA = 40;
    __shared__ __half AS[128 * LDA];
    __shared__ __half BH[64 * LDA];
    __shared__ __half BL[64 * LDA];

    int tid  = threadIdx.x;
    int lane = tid & 63;
    int wave = tid >> 6;
    int wr = wave & 1, wc = wave >> 1;
    int quad = lane >> 4, r = lane & 15;
    int r0 = blockIdx.x * 128, c0 = blockIdx.y * 64;

    f32x4 acc[4][2];
#pragma unroll
    for (int i = 0; i < 4; ++i)
#pragma unroll
        for (int j = 0; j < 2; ++j) acc[i][j] = (f32x4){0.f, 0.f, 0.f, 0.f};

    for (int kc = 0; kc < K; kc += 32) {
#pragma unroll
        for (int it = 0; it < 2; ++it) {
            int row  = (tid >> 2) + it * 64;
            int kseg = (tid & 3) * 8;
            int gr = r0 + row;
            f16x8 v = (f16x8)(_Float16)0;
            if (gr < nrows) v = *reinterpret_cast<const f16x8*>(A + (size_t)gr * K + kc + kseg);
            *reinterpret_cast<f16x8*>(&AS[row * LDA + kseg]) = v;
        }
        {
            int n    = tid >> 2;
            int kseg = (tid & 3) * 8;
            *reinterpret_cast<f16x8*>(&BH[n * LDA + kseg]) =
                *reinterpret_cast<const f16x8*>(Wth + (size_t)(c0 + n) * K + kc + kseg);
            *reinterpret_cast<f16x8*>(&BL[n * LDA + kseg]) =
                *reinterpret_cast<const f16x8*>(Wtl + (size_t)(c0 + n) * K + kc + kseg);
        }
        __syncthreads();
        int k0 = quad * 8;
        f16x8 a[4], bh[2], bl[2];
#pragma unroll
        for (int tr = 0; tr < 4; ++tr) {
            int row = wr * 64 + tr * 16 + r;
            a[tr] = *reinterpret_cast<const f16x8*>(&AS[row * LDA + k0]);
        }
#pragma unroll
        for (int tc = 0; tc < 2; ++tc) {
            int col = wc * 32 + tc * 16 + r;
            bh[tc] = *reinterpret_cast<const f16x8*>(&BH[col * LDA + k0]);
            bl[tc] = *reinterpret_cast<const f16x8*>(&BL[col * LDA + k0]);
        }
#pragma unroll
        for (int tr = 0; tr < 4; ++tr)
#pragma unroll
            for (int tc = 0; tc < 2; ++tc) {
                acc[tr][tc] = __builtin_amdgcn_mfma_f32_16x16x32_f16(a[tr], bh[tc], acc[tr][tc], 0, 0, 0);
                acc[tr][tc] = __builtin_amdgcn_mfma_f32_16x16x32_f16(a[tr], bl[tc], acc[tr][tc], 0, 0, 0);
            }
        __syncthreads();
    }
#pragma unroll
    for (int tr = 0; tr < 4; ++tr)
#pragma unroll
        for (int tc = 0; tc < 2; ++tc) {
            int col = c0 + wc * 32 + tc * 16 + r;
#pragma unroll
            for (int i = 0; i < 4; ++i) {
                int row = r0 + wr * 64 + tr * 16 + quad * 4 + i;
                if (row < nrows) C[(size_t)row * M + col] = __float2half(acc[tr][tc][i]);
            }
        }
}

// ---------------- attention coefficients ----------------
template <int CHUNK>
__global__ void k_alpha(const __half* __restrict__ feat, const float* __restrict__ a_src,
                        const float* __restrict__ a_dst, float* __restrict__ als,
                        float* __restrict__ ald, int N) {
    constexpr int M = 64 * CHUNK;
    constexpr int H = M / 64;
    constexpr int WIDTH = 64 / H;
    int lane = threadIdx.x & 63;
    int node = blockIdx.x * 4 + (threadIdx.x >> 6);
    if (node >= N) return;
    float f[CHUNK];
    ldrow<CHUNK>(feat + (size_t)node * M + lane * CHUNK, f);
    float ps = 0.f, pd = 0.f;
#pragma unroll
    for (int j = 0; j < CHUNK; ++j) {
        int col = lane * CHUNK + j;
        ps += f[j] * a_src[col];
        pd += f[j] * a_dst[col];
    }
#pragma unroll
    for (int off = 1; off < WIDTH; off <<= 1) {
        ps += __shfl_xor(ps, off, 64);
        pd += __shfl_xor(pd, off, 64);
    }
    if ((lane & (WIDTH - 1)) == 0) {
        int head = lane / WIDTH;
        als[(size_t)node * H + head] = ps;
        ald[(size_t)node * H + head] = pd;
    }
}

// ---------------- GAT aggregation: full-wave lane-parallel weights, EC=16 ----------------
// Phase A: 16 edges x H heads of weight computation mapped onto all 64 lanes
// (CHUNK=4: lane = ha*16+ia, one exp per edge-head pair, no duplicated work).
// Weights + 32-bit row byte-offsets round-trip through wave-private LDS
// (no barriers; DS ops are in-order within a wave).
// Phase B: fully-unrolled 16-edge gather + FMA. Tail-chunk clamped-duplicate
// loads are branch-skipped via a readfirstlane'd (SGPR) count; skipped slots
// substitute v=0 so FMAs compute fmaf(0,0,acc) == round-2's fmaf(row,0,acc)
// -> bit-identical output, fewer memory-pipe issues.
template <int CHUNK, bool ELU, typename OT>
__global__ void k_agg(const __half* __restrict__ feat, const int* __restrict__ offs,
                      const int* __restrict__ csr, const float* __restrict__ als,
                      const float* __restrict__ ald, const float* __restrict__ bias,
                      OT* __restrict__ out, int N) {
    constexpr int M  = 64 * CHUNK;              // 256 or 64
    constexpr int H  = (CHUNK == 4) ? 4 : 1;
    constexpr int EC = 16;                      // edges per chunk
    constexpr int SH = (CHUNK == 4) ? 9 : 7;    // log2(M * sizeof(__half))

    __shared__ float    shw[4][2][64];
    __shared__ unsigned sho[4][2][EC];

    int tid  = threadIdx.x;
    int lane = tid & 63;
    int wid  = tid >> 6;
    int node = blockIdx.x * 4 + wid;
    if (node >= N) return;

    int ia = lane & 15;                          // edge slot in phase A
    int ha = (H == 4) ? (lane >> 4) : 0;         // head in phase A (CHUNK=1: groups duplicate)
    int ho = lane >> 4;                          // 16-lane group id == output head (CHUNK=4)

    float adv = ald[(size_t)node * H + ha];

    int beg = offs[node], end = offs[node + 1];
    int d   = end - beg;                         // >= 1 (self-loop)
    int nc  = (d + EC - 1) >> 4;

    const char* fbase = reinterpret_cast<const char*>(feat) + lane * (CHUNK * 2);

    float acc[CHUNK] = {};
    float den = 0.f;

    // prologue: chunk 0 src + logit, chunk 1 src
    int sv = csr[beg + min(ia, min(EC, d) - 1)];
    float xv = als[(size_t)sv * H + ha];
    int sv_n = sv;
    if (nc > 1) {
        int cn = min(EC, d - EC);
        sv_n = csr[beg + EC + min(ia, cn - 1)];
    }

    for (int c = 0; c < nc; ++c) {
        int cnt = min(EC, d - c * EC);

        // ---- phase A: one weight per lane (edge ia, head ha) ----
        float e = xv + adv;
        e = (e > 0.f) ? e : 0.2f * e;
        float w = (ia < cnt) ? __expf(e) : 0.f;
        den += w;
        int b = c & 1;
        shw[wid][b][lane] = w;                   // full-wave ds_write, no predicate
        if (lane < EC) sho[wid][b][lane] = (unsigned)sv << SH;

        // prefetch: logit for chunk c+1 (issued before phase B), src for chunk c+2
        xv = als[(size_t)sv_n * H + ha];
        sv = sv_n;
        if (c + 2 < nc) {
            int cn = min(EC, d - (c + 2) * EC);
            sv_n = csr[beg + (c + 2) * EC + min(ia, cn - 1)];
        }

        // ---- phase B: broadcast-read weights/offsets, 16-deep gather+FMA ----
        int cnts = __builtin_amdgcn_readfirstlane(cnt);   // wave-uniform count -> SGPR
        const float* wp = &shw[wid][b][ho * EC];
        float4 w0 = *reinterpret_cast<const float4*>(wp);
        float4 w1 = *reinterpret_cast<const float4*>(wp + 4);
        float4 w2 = *reinterpret_cast<const float4*>(wp + 8);
        float4 w3 = *reinterpret_cast<const float4*>(wp + 12);
        const unsigned* op = &sho[wid][b][0];
        uint4 o0 = *reinterpret_cast<const uint4*>(op);
        uint4 o1 = *reinterpret_cast<const uint4*>(op + 4);
        uint4 o2 = *reinterpret_cast<const uint4*>(op + 8);
        uint4 o3 = *reinterpret_cast<const uint4*>(op + 12);
        float    ww[EC] = {w0.x, w0.y, w0.z, w0.w, w1.x, w1.y, w1.z, w1.w,
                           w2.x, w2.y, w2.z, w2.w, w3.x, w3.y, w3.z, w3.w};
        unsigned oo[EC] = {o0.x, o0.y, o0.z, o0.w, o1.x, o1.y, o1.z, o1.w,
                           o2.x, o2.y, o2.z, o2.w, o3.x, o3.y, o3.z, o3.w};
        if constexpr (CHUNK == 4) {
            f16x4 v[EC];
#pragma unroll
            for (int t = 0; t < EC; ++t) {
                if (t < cnts) v[t] = *reinterpret_cast<const f16x4*>(fbase + oo[t]);
                else          v[t] = (f16x4)(_Float16)0;
            }
#pragma unroll
            for (int t = 0; t < EC; ++t)
#pragma unroll
                for (int j = 0; j < 4; ++j)
                    acc[j] = fmaf((float)v[t][j], ww[t], acc[j]);
        } else {
            __half v[EC];
#pragma unroll
            for (int t = 0; t < EC; ++t) {
                if (t < cnts) v[t] = *reinterpret_cast<const __half*>(fbase + oo[t]);
                else          v[t] = __ushort_as_half((unsigned short)0);
            }
#pragma unroll
            for (int t = 0; t < EC; ++t)
                acc[0] = fmaf(__half2float(v[t]), ww[t], acc[0]);
        }
    }

    // denominator: reduce within aligned 16-lane groups (group == head for CHUNK=4;
    // CHUNK=1: each group independently computed all edge weights -> full sum)
#pragma unroll
    for (int off = 1; off < EC; off <<= 1) den += __shfl_xor(den, off, 64);
    float inv = 1.f / (den + 1e-16f);

#pragma unroll
    for (int j = 0; j < CHUNK; ++j) {
        int col = lane * CHUNK + j;
        float v = acc[j] * inv + bias[col];
        if (ELU) v = (v > 0.f) ? v : (__expf(v) - 1.f);
        st(&out[(size_t)node * M + col], v);
    }
}

// ---------------- global mean pool: batch sorted -> one block per graph ----------------
static __device__ __forceinline__ int lowerb(const int* __restrict__ a, int n, int v) {
    int lo = 0, hi = n;
    while (lo < hi) { int mid = (lo + hi) >> 1; if (a[mid] < v) lo = mid + 1; else hi = mid; }
    return lo;
}

__global__ void k_pool2(const float* __restrict__ ne, const int* __restrict__ batch,
                        float* __restrict__ gout, int N) {
    int g = blockIdx.x;
    int lo = lowerb(batch, N, g);
    int hi = lowerb(batch, N, g + 1);
    int lane = threadIdx.x & 63, row = threadIdx.x >> 6;
    float s = 0.f;
    for (int i = lo + row; i < hi; i += 4) s += ne[(size_t)i * 64 + lane];
    __shared__ float red[4][64];
    red[row][lane] = s;
    __syncthreads();
    if (row == 0) {
        float v = red[0][lane] + red[1][lane] + red[2][lane] + red[3][lane];
        gout[(size_t)g * 64 + lane] = v / fmaxf((float)(hi - lo), 1.f);
    }
}

extern "C" void kernel_launch(void* const* d_in, const int* in_sizes, int n_in,
                              void* d_out, int out_size, void* d_ws, size_t ws_size,
                              hipStream_t stream) {
    const float* x   = (const float*)d_in[0];
    const int* ei    = (const int*)d_in[1];
    const int* batch = (const int*)d_in[2];
    const float* W1  = (const float*)d_in[3];
    const float* as1 = (const float*)d_in[4];
    const float* ad1 = (const float*)d_in[5];
    const float* b1  = (const float*)d_in[6];
    const float* W2  = (const float*)d_in[7];
    const float* as2 = (const float*)d_in[8];
    const float* ad2 = (const float*)d_in[9];
    const float* b2  = (const float*)d_in[10];
    const float* W3  = (const float*)d_in[11];
    const float* as3 = (const float*)d_in[12];
    const float* ad3 = (const float*)d_in[13];
    const float* b3  = (const float*)d_in[14];

    const int N = in_sizes[2];      // 50000
    const int E = in_sizes[1] / 2;  // 800000
    const int G = 64;
    float* out = (float*)d_out;

    // workspace (~85 MB). act aliases xh (xh/xl dead after layer-1 GEMM).
    char* w = (char*)d_ws;
    auto carve = [&](size_t bytes) { char* p = w; w += (bytes + 255) & ~(size_t)255; return p; };
    __half* feat = (__half*)carve((size_t)N * 256 * 2);   // GEMM output (f16)
    __half* xh   = (__half*)carve((size_t)N * 256 * 2);   // layer-1 A hi; later act
    __half* xl   = (__half*)carve((size_t)N * 256 * 2);   // layer-1 A lo
    __half* act  = xh;                                     // alias: safe after gemm3
    float* als   = (float*)carve((size_t)N * 4 * 4);
    float* ald   = (float*)carve((size_t)N * 4 * 4);
    int* deg     = (int*)carve((size_t)N * 4);
    int* offs    = (int*)carve((size_t)(N + 1) * 4);
    int* cursor  = (int*)carve((size_t)N * 4);
    int* csr     = (int*)carve((size_t)(E + N) * 4);
    int nb       = (N + 255) / 256;
    int* bsum    = (int*)carve((size_t)(nb + 1) * 4);
    __half* w1h  = (__half*)carve((size_t)256 * 256 * 2);
    __half* w1l  = (__half*)carve((size_t)256 * 256 * 2);
    __half* w2h  = (__half*)carve((size_t)256 * 256 * 2);
    __half* w2l  = (__half*)carve((size_t)256 * 256 * 2);
    __half* w3h  = (__half*)carve((size_t)256 * 64 * 2);
    __half* w3l  = (__half*)carve((size_t)256 * 64 * 2);

    // CSR build
    k_init<<<(N + 255) / 256, 256, 0, stream>>>(deg, N);
    k_hist<<<(E + 255) / 256, 256, 0, stream>>>(ei, deg, E);
    k_scan1<<<nb, 256, 0, stream>>>(deg, offs, bsum, N);
    k_scan2<<<1, 256, 0, stream>>>(bsum, nb);
    k_scan3<<<nb, 256, 0, stream>>>(offs, cursor, bsum, N, nb);
    k_scatter<<<(E + 255) / 256, 256, 0, stream>>>(ei, cursor, csr, E);
    k_scatter_loops<<<(N + 255) / 256, 256, 0, stream>>>(cursor, csr, N);

    // pre-split weights (transposed, f16 hi/lo) and layer-1 input
    k_wsplit<<<(256 * 256 + 255) / 256, 256, 0, stream>>>(W1, w1h, w1l, 256, 256);
    k_wsplit<<<(256 * 256 + 255) / 256, 256, 0, stream>>>(W2, w2h, w2l, 256, 256);
    k_wsplit<<<(256 * 64 + 255) / 256, 256, 0, stream>>>(W3, w3h, w3l, 256, 64);
    long n4 = (long)N * 64;   // N*256/4 float4 groups
    k_xsplit<<<(int)((n4 + 255) / 256), 256, 0, stream>>>(x, xh, xl, n4);

    dim3 gemmBig((N + 127) / 128, 4);
    dim3 gemmSmall((N + 127) / 128, 1);
    int nodeBlocks = (N + 3) / 4;

    // layer 1 (3-term A split)
    k_gemm3<<<gemmBig, 256, 0, stream>>>(xh, xl, w1h, w1l, feat, N, 256, 256);
    k_alpha<4><<<nodeBlocks, 256, 0, stream>>>(feat, as1, ad1, als, ald, N);
    k_agg<4, true, __half><<<nodeBlocks, 256, 0, stream>>>(feat, offs, csr, als, ald, b1, act, N);
    // layer 2 (A exact f16, 2-term)
    k_gemm2<<<gemmBig, 256, 0, stream>>>(act, w2h, w2l, feat, N, 256, 256);
    k_alpha<4><<<nodeBlocks, 256, 0, stream>>>(feat, as2, ad2, als, ald, N);
    k_agg<4, true, __half><<<nodeBlocks, 256, 0, stream>>>(feat, offs, csr, als, ald, b2, act, N);
    // layer 3: 256 -> 64, single head, no ELU; fp32 straight to d_out
    k_gemm2<<<gemmSmall, 256, 0, stream>>>(act, w3h, w3l, feat, N, 256, 64);
    k_alpha<1><<<nodeBlocks, 256, 0, stream>>>(feat, as3, ad3, als, ald, N);
    k_agg<1, false, float><<<nodeBlocks, 256, 0, stream>>>(feat, offs, csr, als, ald, b3, out, N);

    // global mean pool
    k_pool2<<<G, 256, 0, stream>>>(out, batch, out + (size_t)N * 64, N);
}

// Round 5
// 540.960 us; speedup vs baseline: 1.1269x; 1.1269x over previous
//
#include <hip/hip_runtime.h>
#include <hip/hip_bf16.h>
#include <hip/hip_fp16.h>

typedef __attribute__((ext_vector_type(8))) _Float16 f16x8;
typedef __attribute__((ext_vector_type(4))) _Float16 f16x4;
typedef __attribute__((ext_vector_type(4))) float f32x4;

static __device__ __forceinline__ void st(float* p, float v)  { *p = v; }
static __device__ __forceinline__ void st(__half* p, float v) { *p = __float2half(v); }

// fp32 -> f16 hi/lo split (residual <= 2^-22 relative)
static __device__ __forceinline__ void splitf16(float v, __half& hi, __half& lo) {
    hi = __float2half(v);
    lo = __float2half(v - __half2float(hi));
}

// ---------------- CSR build ----------------
__global__ void k_hist(const int* __restrict__ ei, int* deg, int E) {
    int e = blockIdx.x * blockDim.x + threadIdx.x;
    if (e < E) atomicAdd(&deg[ei[E + e]], 1);
}

// deg[] holds edge-degree (memset 0 + atomics); +1 here accounts for the self-loop
__global__ void k_scan1(const int* __restrict__ deg, int* __restrict__ offs,
                        int* __restrict__ bsum, int N) {
    __shared__ int sh[256];
    int i = blockIdx.x * 256 + threadIdx.x;
    int v = (i < N) ? (deg[i] + 1) : 0;
    sh[threadIdx.x] = v;
    __syncthreads();
#pragma unroll
    for (int off = 1; off < 256; off <<= 1) {
        int t = (threadIdx.x >= off) ? sh[threadIdx.x - off] : 0;
        __syncthreads();
        sh[threadIdx.x] += t;
        __syncthreads();
    }
    if (i < N) offs[i] = sh[threadIdx.x] - v;
    if (threadIdx.x == 255) bsum[blockIdx.x] = sh[255];
}

__global__ void k_scan2(int* __restrict__ bsum, int nb) {   // nb <= 256, single block
    __shared__ int sh[256];
    int v = (threadIdx.x < nb) ? bsum[threadIdx.x] : 0;
    sh[threadIdx.x] = v;
    __syncthreads();
#pragma unroll
    for (int off = 1; off < 256; off <<= 1) {
        int t = (threadIdx.x >= off) ? sh[threadIdx.x - off] : 0;
        __syncthreads();
        sh[threadIdx.x] += t;
        __syncthreads();
    }
    if (threadIdx.x < nb) bsum[threadIdx.x] = sh[threadIdx.x] - v;
    if (threadIdx.x == 255) bsum[nb] = sh[255];
}

__global__ void k_scan3(int* __restrict__ offs, int* __restrict__ cursor,
                        const int* __restrict__ bsum, int N, int nb) {
    int i = blockIdx.x * 256 + threadIdx.x;
    if (i < N) {
        int v = offs[i] + bsum[blockIdx.x];
        offs[i] = v;
        cursor[i] = v;
    }
    if (i == 0) offs[N] = bsum[nb];
}

// merged edge-scatter + self-loop-scatter (both order-free atomic appends)
__global__ void k_scatter_all(const int* __restrict__ ei, int* cursor, int* csr,
                              int E, int N) {
    int e = blockIdx.x * blockDim.x + threadIdx.x;
    if (e < E) {
        int d = ei[E + e];
        int p = atomicAdd(&cursor[d], 1);
        csr[p] = ei[e];
    } else if (e < E + N) {
        int i = e - E;
        int p = atomicAdd(&cursor[i], 1);
        csr[p] = i;
    }
}

// ---------------- pre-split kernels (f16 basis) ----------------
// all three weight matrices in one launch: W [K x M] fp32 -> transposed f16 hi/lo [M x K]
__global__ void k_wsplit_all(const float* __restrict__ W1, const float* __restrict__ W2,
                             const float* __restrict__ W3,
                             __half* __restrict__ w1h, __half* __restrict__ w1l,
                             __half* __restrict__ w2h, __half* __restrict__ w2l,
                             __half* __restrict__ w3h, __half* __restrict__ w3l) {
    int idx = blockIdx.x * 256 + threadIdx.x;
    const float* W; __half *Wh, *Wl; int M, base;
    constexpr int K = 256;
    if (idx < 65536)       { W = W1; Wh = w1h; Wl = w1l; M = 256; base = idx; }
    else if (idx < 131072) { W = W2; Wh = w2h; Wl = w2l; M = 256; base = idx - 65536; }
    else if (idx < 147456) { W = W3; Wh = w3h; Wl = w3l; M = 64;  base = idx - 131072; }
    else return;
    int k = base / M, n = base - k * M;
    __half h, l;
    splitf16(W[base], h, l);
    Wh[(size_t)n * K + k] = h;
    Wl[(size_t)n * K + k] = l;
}

// x fp32 -> f16 hi/lo (row-major), vectorized: float4 in, ushort4 out
__global__ void k_xsplit(const float* __restrict__ x, __half* __restrict__ xh,
                         __half* __restrict__ xl, long n4) {
    long i = (long)blockIdx.x * 256 + threadIdx.x;   // in units of 4 floats
    if (i < n4) {
        float4 v = *reinterpret_cast<const float4*>(x + i * 4);
        __half h0, h1, h2, h3, l0, l1, l2, l3;
        splitf16(v.x, h0, l0);
        splitf16(v.y, h1, l1);
        splitf16(v.z, h2, l2);
        splitf16(v.w, h3, l3);
        ushort4 hv = { __half_as_ushort(h0), __half_as_ushort(h1),
                       __half_as_ushort(h2), __half_as_ushort(h3) };
        ushort4 lv = { __half_as_ushort(l0), __half_as_ushort(l1),
                       __half_as_ushort(l2), __half_as_ushort(l3) };
        *reinterpret_cast<ushort4*>(xh + i * 4) = hv;
        *reinterpret_cast<ushort4*>(xl + i * 4) = lv;
    }
}

// ---------------- fused alpha epilogue (shared by both GEMMs) ----------------
// Block tile = 64 cols = exactly one head (head = c0>>6). Computes
// als/ald[row][head] = sum_col f16(C[row][col]) * a[col] from the SAME rounded
// f16 values stored to C -> bit-identical to the old standalone k_alpha pass.
// ldsf: reused (dead) A-tile LDS, needs 2*2*128 floats = 2KB.
template <typename ACC>
static __device__ __forceinline__ void alpha_epilogue(
        const ACC& acc, float* ldsf, const float* __restrict__ a_src,
        const float* __restrict__ a_dst, float* __restrict__ als,
        float* __restrict__ ald, __half* __restrict__ C,
        int nrows, int M, int H, int r0, int c0,
        int wr, int wc, int quad, int r, int tid) {
    float ps[4][4], pd[4][4];
#pragma unroll
    for (int tr = 0; tr < 4; ++tr)
#pragma unroll
        for (int i = 0; i < 4; ++i) { ps[tr][i] = 0.f; pd[tr][i] = 0.f; }

#pragma unroll
    for (int tr = 0; tr < 4; ++tr)
#pragma unroll
        for (int tc = 0; tc < 2; ++tc) {
            int col = c0 + wc * 32 + tc * 16 + r;
            float av_s = a_src[col], av_d = a_dst[col];
#pragma unroll
            for (int i = 0; i < 4; ++i) {
                int row = r0 + wr * 64 + tr * 16 + quad * 4 + i;
                __half hv = __float2half(acc[tr][tc][i]);
                float vr = __half2float(hv);
                if (row < nrows) C[(size_t)row * M + col] = hv;
                ps[tr][i] = fmaf(vr, av_s, ps[tr][i]);
                pd[tr][i] = fmaf(vr, av_d, pd[tr][i]);
            }
        }
    // reduce over the 16 lanes of the quad (r = 0..15 span 16 cols x 2 tc = this wave's 32 cols)
#pragma unroll
    for (int tr = 0; tr < 4; ++tr)
#pragma unroll
        for (int i = 0; i < 4; ++i) {
            float s = ps[tr][i], d2 = pd[tr][i];
#pragma unroll
            for (int off = 1; off < 16; off <<= 1) {
                s  += __shfl_xor(s,  off, 64);
                d2 += __shfl_xor(d2, off, 64);
            }
            if (r == 0) {
                int lrow = wr * 64 + tr * 16 + quad * 4 + i;
                ldsf[(0 * 2 + wc) * 128 + lrow] = s;    // [which][wc][row]
                ldsf[(2 + wc) * 128 + lrow]     = d2;
            }
        }
    __syncthreads();
    int lrow = tid >> 1, which = tid & 1;   // 256 threads -> 128 rows x {src,dst}
    if (lrow < 128) {
        float v = ldsf[(which * 2 + 0) * 128 + lrow] + ldsf[(which * 2 + 1) * 128 + lrow];
        int grow = r0 + lrow;
        if (grow < nrows) {
            float* dst = which ? ald : als;
            dst[(size_t)grow * H + (c0 >> 6)] = v;
        }
    }
}

// ---------------- f16-split MFMA GEMMs ----------------
// Layer 1 (3-term): C = (Ah+Al) @ (Wh+Wl) ~= AhWh + AhWl + AlWh
// BM=128, BN=64, BK=32; 4 waves 2x2; LDA=40 halves (80B, 16B-aligned).
__global__ __launch_bounds__(256) void k_gemm3(const __half* __restrict__ Ah, const __half* __restrict__ Al,
                                               const __half* __restrict__ Wth, const __half* __restrict__ Wtl,
                                               __half* __restrict__ C, int nrows, int K, int M,
                                               const float* __restrict__ a_src, const float* __restrict__ a_dst,
                                               float* __restrict__ als, float* __restrict__ ald, int H) {
    constexpr int LDA = 40;
    __shared__ __half AH[128 * LDA];
    __shared__ __half AL[128 * LDA];
    __shared__ __half BH[64 * LDA];
    __shared__ __half BL[64 * LDA];

    int tid  = threadIdx.x;
    int lane = tid & 63;
    int wave = tid >> 6;
    int wr = wave & 1, wc = wave >> 1;
    int quad = lane >> 4, r = lane & 15;
    int r0 = blockIdx.x * 128, c0 = blockIdx.y * 64;

    f32x4 acc[4][2];
#pragma unroll
    for (int i = 0; i < 4; ++i)
#pragma unroll
        for (int j = 0; j < 2; ++j) acc[i][j] = (f32x4){0.f, 0.f, 0.f, 0.f};

    for (int kc = 0; kc < K; kc += 32) {
#pragma unroll
        for (int it = 0; it < 2; ++it) {
            int row  = (tid >> 2) + it * 64;
            int kseg = (tid & 3) * 8;
            int gr = r0 + row;
            f16x8 vh = (f16x8)(_Float16)0, vl = (f16x8)(_Float16)0;
            if (gr < nrows) {
                vh = *reinterpret_cast<const f16x8*>(Ah + (size_t)gr * K + kc + kseg);
                vl = *reinterpret_cast<const f16x8*>(Al + (size_t)gr * K + kc + kseg);
            }
            *reinterpret_cast<f16x8*>(&AH[row * LDA + kseg]) = vh;
            *reinterpret_cast<f16x8*>(&AL[row * LDA + kseg]) = vl;
        }
        {
            int n    = tid >> 2;
            int kseg = (tid & 3) * 8;
            *reinterpret_cast<f16x8*>(&BH[n * LDA + kseg]) =
                *reinterpret_cast<const f16x8*>(Wth + (size_t)(c0 + n) * K + kc + kseg);
            *reinterpret_cast<f16x8*>(&BL[n * LDA + kseg]) =
                *reinterpret_cast<const f16x8*>(Wtl + (size_t)(c0 + n) * K + kc + kseg);
        }
        __syncthreads();
        int k0 = quad * 8;
        f16x8 ah[4], al[4], bh[2], bl[2];
#pragma unroll
        for (int tr = 0; tr < 4; ++tr) {
            int row = wr * 64 + tr * 16 + r;
            ah[tr] = *reinterpret_cast<const f16x8*>(&AH[row * LDA + k0]);
            al[tr] = *reinterpret_cast<const f16x8*>(&AL[row * LDA + k0]);
        }
#pragma unroll
        for (int tc = 0; tc < 2; ++tc) {
            int col = wc * 32 + tc * 16 + r;
            bh[tc] = *reinterpret_cast<const f16x8*>(&BH[col * LDA + k0]);
            bl[tc] = *reinterpret_cast<const f16x8*>(&BL[col * LDA + k0]);
        }
#pragma unroll
        for (int tr = 0; tr < 4; ++tr)
#pragma unroll
            for (int tc = 0; tc < 2; ++tc) {
                acc[tr][tc] = __builtin_amdgcn_mfma_f32_16x16x32_f16(ah[tr], bh[tc], acc[tr][tc], 0, 0, 0);
                acc[tr][tc] = __builtin_amdgcn_mfma_f32_16x16x32_f16(ah[tr], bl[tc], acc[tr][tc], 0, 0, 0);
                acc[tr][tc] = __builtin_amdgcn_mfma_f32_16x16x32_f16(al[tr], bh[tc], acc[tr][tc], 0, 0, 0);
            }
        __syncthreads();
    }
    alpha_epilogue(acc, reinterpret_cast<float*>(AH), a_src, a_dst, als, ald, C,
                   nrows, M, H, r0, c0, wr, wc, quad, r, tid);
}

// Layers 2/3 (2-term): A is exact f16 -> C = A @ (Wh+Wl). LDS ~20.5 KB.
__global__ __launch_bounds__(256) void k_gemm2(const __half* __restrict__ A,
                                               const __half* __restrict__ Wth, const __half* __restrict__ Wtl,
                                               __half* __restrict__ C, int nrows, int K, int M,
                                               const float* __restrict__ a_src, const float* __restrict__ a_dst,
                                               float* __restrict__ als, float* __restrict__ ald, int H) {
    constexpr int LDA = 40;
    __shared__ __half AS[128 * LDA];
    __shared__ __half BH[64 * LDA];
    __shared__ __half BL[64 * LDA];

    int tid  = threadIdx.x;
    int lane = tid & 63;
    int wave = tid >> 6;
    int wr = wave & 1, wc = wave >> 1;
    int quad = lane >> 4, r = lane & 15;
    int r0 = blockIdx.x * 128, c0 = blockIdx.y * 64;

    f32x4 acc[4][2];
#pragma unroll
    for (int i = 0; i < 4; ++i)
#pragma unroll
        for (int j = 0; j < 2; ++j) acc[i][j] = (f32x4){0.f, 0.f, 0.f, 0.f};

    for (int kc = 0; kc < K; kc += 32) {
#pragma unroll
        for (int it = 0; it < 2; ++it) {
            int row  = (tid >> 2) + it * 64;
            int kseg = (tid & 3) * 8;
            int gr = r0 + row;
            f16x8 v = (f16x8)(_Float16)0;
            if (gr < nrows) v = *reinterpret_cast<const f16x8*>(A + (size_t)gr * K + kc + kseg);
            *reinterpret_cast<f16x8*>(&AS[row * LDA + kseg]) = v;
        }
        {
            int n    = tid >> 2;
            int kseg = (tid & 3) * 8;
            *reinterpret_cast<f16x8*>(&BH[n * LDA + kseg]) =
                *reinterpret_cast<const f16x8*>(Wth + (size_t)(c0 + n) * K + kc + kseg);
            *reinterpret_cast<f16x8*>(&BL[n * LDA + kseg]) =
                *reinterpret_cast<const f16x8*>(Wtl + (size_t)(c0 + n) * K + kc + kseg);
        }
        __syncthreads();
        int k0 = quad * 8;
        f16x8 a[4], bh[2], bl[2];
#pragma unroll
        for (int tr = 0; tr < 4; ++tr) {
            int row = wr * 64 + tr * 16 + r;
            a[tr] = *reinterpret_cast<const f16x8*>(&AS[row * LDA + k0]);
        }
#pragma unroll
        for (int tc = 0; tc < 2; ++tc) {
            int col = wc * 32 + tc * 16 + r;
            bh[tc] = *reinterpret_cast<const f16x8*>(&BH[col * LDA + k0]);
            bl[tc] = *reinterpret_cast<const f16x8*>(&BL[col * LDA + k0]);
        }
#pragma unroll
        for (int tr = 0; tr < 4; ++tr)
#pragma unroll
            for (int tc = 0; tc < 2; ++tc) {
                acc[tr][tc] = __builtin_amdgcn_mfma_f32_16x16x32_f16(a[tr], bh[tc], acc[tr][tc], 0, 0, 0);
                acc[tr][tc] = __builtin_amdgcn_mfma_f32_16x16x32_f16(a[tr], bl[tc], acc[tr][tc], 0, 0, 0);
            }
        __syncthreads();
    }
    alpha_epilogue(acc, reinterpret_cast<float*>(AS), a_src, a_dst, als, ald, C,
                   nrows, M, H, r0, c0, wr, wc, quad, r, tid);
}

// ---------------- GAT aggregation: full-wave lane-parallel weights, EC=16 ----------------
// (Round-2 proven version, verbatim.) Phase A: 16 edges x H heads of weight
// computation mapped onto all 64 lanes. Weights + 32-bit row byte-offsets
// round-trip through wave-private LDS (no barriers; DS ops in-order per wave).
// Phase B: fully-unrolled 16-edge gather (16 independent 8B loads in flight) + FMA.
// Tail chunks clamp padded lanes to the last valid edge (dup loads = L1 hits), w = 0.
template <int CHUNK, bool ELU, typename OT>
__global__ void k_agg(const __half* __restrict__ feat, const int* __restrict__ offs,
                      const int* __restrict__ csr, const float* __restrict__ als,
                      const float* __restrict__ ald, const float* __restrict__ bias,
                      OT* __restrict__ out, int N) {
    constexpr int M  = 64 * CHUNK;              // 256 or 64
    constexpr int H  = (CHUNK == 4) ? 4 : 1;
    constexpr int EC = 16;                      // edges per chunk
    constexpr int SH = (CHUNK == 4) ? 9 : 7;    // log2(M * sizeof(__half))

    __shared__ float    shw[4][2][64];
    __shared__ unsigned sho[4][2][EC];

    int tid  = threadIdx.x;
    int lane = tid & 63;
    int wid  = tid >> 6;
    int node = blockIdx.x * 4 + wid;
    if (node >= N) return;

    int ia = lane & 15;                          // edge slot in phase A
    int ha = (H == 4) ? (lane >> 4) : 0;         // head in phase A (CHUNK=1: groups duplicate)
    int ho = lane >> 4;                          // 16-lane group id == output head (CHUNK=4)

    float adv = ald[(size_t)node * H + ha];

    int beg = offs[node], end = offs[node + 1];
    int d   = end - beg;                         // >= 1 (self-loop)
    int nc  = (d + EC - 1) >> 4;

    const char* fbase = reinterpret_cast<const char*>(feat) + lane * (CHUNK * 2);

    float acc[CHUNK] = {};
    float den = 0.f;

    // prologue: chunk 0 src + logit, chunk 1 src
    int sv = csr[beg + min(ia, min(EC, d) - 1)];
    float xv = als[(size_t)sv * H + ha];
    int sv_n = sv;
    if (nc > 1) {
        int cn = min(EC, d - EC);
        sv_n = csr[beg + EC + min(ia, cn - 1)];
    }

    for (int c = 0; c < nc; ++c) {
        int cnt = min(EC, d - c * EC);

        // ---- phase A: one weight per lane (edge ia, head ha) ----
        float e = xv + adv;
        e = (e > 0.f) ? e : 0.2f * e;
        float w = (ia < cnt) ? __expf(e) : 0.f;
        den += w;
        int b = c & 1;
        shw[wid][b][lane] = w;                   // full-wave ds_write, no predicate
        if (lane < EC) sho[wid][b][lane] = (unsigned)sv << SH;

        // prefetch: logit for chunk c+1 (issued before phase B), src for chunk c+2
        xv = als[(size_t)sv_n * H + ha];
        sv = sv_n;
        if (c + 2 < nc) {
            int cn = min(EC, d - (c + 2) * EC);
            sv_n = csr[beg + (c + 2) * EC + min(ia, cn - 1)];
        }

        // ---- phase B: broadcast-read weights/offsets, 16-deep gather+FMA ----
        const float* wp = &shw[wid][b][ho * EC];
        float4 w0 = *reinterpret_cast<const float4*>(wp);
        float4 w1 = *reinterpret_cast<const float4*>(wp + 4);
        float4 w2 = *reinterpret_cast<const float4*>(wp + 8);
        float4 w3 = *reinterpret_cast<const float4*>(wp + 12);
        const unsigned* op = &sho[wid][b][0];
        uint4 o0 = *reinterpret_cast<const uint4*>(op);
        uint4 o1 = *reinterpret_cast<const uint4*>(op + 4);
        uint4 o2 = *reinterpret_cast<const uint4*>(op + 8);
        uint4 o3 = *reinterpret_cast<const uint4*>(op + 12);
        float    ww[EC] = {w0.x, w0.y, w0.z, w0.w, w1.x, w1.y, w1.z, w1.w,
                           w2.x, w2.y, w2.z, w2.w, w3.x, w3.y, w3.z, w3.w};
        unsigned oo[EC] = {o0.x, o0.y, o0.z, o0.w, o1.x, o1.y, o1.z, o1.w,
                           o2.x, o2.y, o2.z, o2.w, o3.x, o3.y, o3.z, o3.w};
        if constexpr (CHUNK == 4) {
            f16x4 v[EC];
#pragma unroll
            for (int t = 0; t < EC; ++t)
                v[t] = *reinterpret_cast<const f16x4*>(fbase + oo[t]);
#pragma unroll
            for (int t = 0; t < EC; ++t)
#pragma unroll
                for (int j = 0; j < 4; ++j)
                    acc[j] = fmaf((float)v[t][j], ww[t], acc[j]);
        } else {
            __half v[EC];
#pragma unroll
            for (int t = 0; t < EC; ++t)
                v[t] = *reinterpret_cast<const __half*>(fbase + oo[t]);
#pragma unroll
            for (int t = 0; t < EC; ++t)
                acc[0] = fmaf(__half2float(v[t]), ww[t], acc[0]);
        }
    }

    // denominator: reduce within aligned 16-lane groups (group == head for CHUNK=4;
    // CHUNK=1: each group independently computed all edge weights -> full sum)
#pragma unroll
    for (int off = 1; off < EC; off <<= 1) den += __shfl_xor(den, off, 64);
    float inv = 1.f / (den + 1e-16f);

#pragma unroll
    for (int j = 0; j < CHUNK; ++j) {
        int col = lane * CHUNK + j;
        float v = acc[j] * inv + bias[col];
        if (ELU) v = (v > 0.f) ? v : (__expf(v) - 1.f);
        st(&out[(size_t)node * M + col], v);
    }
}

// ---------------- global mean pool: batch sorted -> one block per graph ----------------
static __device__ __forceinline__ int lowerb(const int* __restrict__ a, int n, int v) {
    int lo = 0, hi = n;
    while (lo < hi) { int mid = (lo + hi) >> 1; if (a[mid] < v) lo = mid + 1; else hi = mid; }
    return lo;
}

__global__ void k_pool2(const float* __restrict__ ne, const int* __restrict__ batch,
                        float* __restrict__ gout, int N) {
    int g = blockIdx.x;
    int lo = lowerb(batch, N, g);
    int hi = lowerb(batch, N, g + 1);
    int lane = threadIdx.x & 63, row = threadIdx.x >> 6;
    float s = 0.f;
    for (int i = lo + row; i < hi; i += 4) s += ne[(size_t)i * 64 + lane];
    __shared__ float red[4][64];
    red[row][lane] = s;
    __syncthreads();
    if (row == 0) {
        float v = red[0][lane] + red[1][lane] + red[2][lane] + red[3][lane];
        gout[(size_t)g * 64 + lane] = v / fmaxf((float)(hi - lo), 1.f);
    }
}

extern "C" void kernel_launch(void* const* d_in, const int* in_sizes, int n_in,
                              void* d_out, int out_size, void* d_ws, size_t ws_size,
                              hipStream_t stream) {
    const float* x   = (const float*)d_in[0];
    const int* ei    = (const int*)d_in[1];
    const int* batch = (const int*)d_in[2];
    const float* W1  = (const float*)d_in[3];
    const float* as1 = (const float*)d_in[4];
    const float* ad1 = (const float*)d_in[5];
    const float* b1  = (const float*)d_in[6];
    const float* W2  = (const float*)d_in[7];
    const float* as2 = (const float*)d_in[8];
    const float* ad2 = (const float*)d_in[9];
    const float* b2  = (const float*)d_in[10];
    const float* W3  = (const float*)d_in[11];
    const float* as3 = (const float*)d_in[12];
    const float* ad3 = (const float*)d_in[13];
    const float* b3  = (const float*)d_in[14];

    const int N = in_sizes[2];      // 50000
    const int E = in_sizes[1] / 2;  // 800000
    const int G = 64;
    float* out = (float*)d_out;

    // workspace (~85 MB). act aliases xh (xh/xl dead after layer-1 GEMM).
    char* w = (char*)d_ws;
    auto carve = [&](size_t bytes) { char* p = w; w += (bytes + 255) & ~(size_t)255; return p; };
    __half* feat = (__half*)carve((size_t)N * 256 * 2);   // GEMM output (f16)
    __half* xh   = (__half*)carve((size_t)N * 256 * 2);   // layer-1 A hi; later act
    __half* xl   = (__half*)carve((size_t)N * 256 * 2);   // layer-1 A lo
    __half* act  = xh;                                     // alias: safe after gemm3
    float* als   = (float*)carve((size_t)N * 4 * 4);
    float* ald   = (float*)carve((size_t)N * 4 * 4);
    int* deg     = (int*)carve((size_t)N * 4);
    int* offs    = (int*)carve((size_t)(N + 1) * 4);
    int* cursor  = (int*)carve((size_t)N * 4);
    int* csr     = (int*)carve((size_t)(E + N) * 4);
    int nb       = (N + 255) / 256;
    int* bsum    = (int*)carve((size_t)(nb + 1) * 4);
    __half* w1h  = (__half*)carve((size_t)256 * 256 * 2);
    __half* w1l  = (__half*)carve((size_t)256 * 256 * 2);
    __half* w2h  = (__half*)carve((size_t)256 * 256 * 2);
    __half* w2l  = (__half*)carve((size_t)256 * 256 * 2);
    __half* w3h  = (__half*)carve((size_t)256 * 64 * 2);
    __half* w3l  = (__half*)carve((size_t)256 * 64 * 2);

    // CSR build (deg via memset + edge histogram; +1 self-loop folded into scan1)
    hipMemsetAsync(deg, 0, (size_t)N * 4, stream);
    k_hist<<<(E + 255) / 256, 256, 0, stream>>>(ei, deg, E);
    k_scan1<<<nb, 256, 0, stream>>>(deg, offs, bsum, N);
    k_scan2<<<1, 256, 0, stream>>>(bsum, nb);
    k_scan3<<<nb, 256, 0, stream>>>(offs, cursor, bsum, N, nb);
    k_scatter_all<<<(E + N + 255) / 256, 256, 0, stream>>>(ei, cursor, csr, E, N);

    // pre-split weights (transposed, f16 hi/lo) and layer-1 input
    k_wsplit_all<<<(147456 + 255) / 256, 256, 0, stream>>>(W1, W2, W3, w1h, w1l, w2h, w2l, w3h, w3l);
    long n4 = (long)N * 64;   // N*256/4 float4 groups
    k_xsplit<<<(int)((n4 + 255) / 256), 256, 0, stream>>>(x, xh, xl, n4);

    dim3 gemmBig((N + 127) / 128, 4);
    dim3 gemmSmall((N + 127) / 128, 1);
    int nodeBlocks = (N + 3) / 4;

    // layer 1 (3-term A split; alpha fused in epilogue)
    k_gemm3<<<gemmBig, 256, 0, stream>>>(xh, xl, w1h, w1l, feat, N, 256, 256,
                                         as1, ad1, als, ald, 4);
    k_agg<4, true, __half><<<nodeBlocks, 256, 0, stream>>>(feat, offs, csr, als, ald, b1, act, N);
    // layer 2 (A exact f16, 2-term; alpha fused)
    k_gemm2<<<gemmBig, 256, 0, stream>>>(act, w2h, w2l, feat, N, 256, 256,
                                         as2, ad2, als, ald, 4);
    k_agg<4, true, __half><<<nodeBlocks, 256, 0, stream>>>(feat, offs, csr, als, ald, b2, act, N);
    // layer 3: 256 -> 64, single head, no ELU; fp32 straight to d_out
    k_gemm2<<<gemmSmall, 256, 0, stream>>>(act, w3h, w3l, feat, N, 256, 64,
                                           as3, ad3, als, ald, 1);
    k_agg<1, false, float><<<nodeBlocks, 256, 0, stream>>>(feat, offs, csr, als, ald, b3, out, N);

    // global mean pool
    k_pool2<<<G, 256, 0, stream>>>(out, batch, out + (size_t)N * 64, N);
}

// Round 6
// 497.124 us; speedup vs baseline: 1.2262x; 1.0882x over previous
//
#include <hip/hip_runtime.h>
#include <hip/hip_bf16.h>
#include <hip/hip_fp16.h>

typedef __attribute__((ext_vector_type(8))) _Float16 f16x8;
typedef __attribute__((ext_vector_type(4))) _Float16 f16x4;
typedef __attribute__((ext_vector_type(4))) float f32x4;

static __device__ __forceinline__ void st(float* p, float v)  { *p = v; }
static __device__ __forceinline__ void st(__half* p, float v) { *p = __float2half(v); }

// fp32 -> f16 hi/lo split (residual <= 2^-22 relative)
static __device__ __forceinline__ void splitf16(float v, __half& hi, __half& lo) {
    hi = __float2half(v);
    lo = __float2half(v - __half2float(hi));
}

// ---------------- fused pre-pass: edge histogram(+rank) | x split | W splits ----------------
// All three are mutually independent; one launch lets the BW-bound splits hide
// under the latency-bound histogram atomics.
__global__ void k_pre(const int* __restrict__ ei, int* __restrict__ deg, int* __restrict__ rnk,
                      int E,
                      const float* __restrict__ x, __half* __restrict__ xh,
                      __half* __restrict__ xl, long n4,
                      const float* __restrict__ W1, const float* __restrict__ W2,
                      const float* __restrict__ W3,
                      __half* __restrict__ w1h, __half* __restrict__ w1l,
                      __half* __restrict__ w2h, __half* __restrict__ w2l,
                      __half* __restrict__ w3h, __half* __restrict__ w3l) {
    int bx = blockIdx.x;
    int nhist = (E + 255) >> 8;
    if (bx < nhist) {
        int e = bx * 256 + threadIdx.x;
        if (e < E) rnk[e] = atomicAdd(&deg[ei[E + e]], 1);   // rank within dst segment
        return;
    }
    bx -= nhist;
    int nx4 = (int)((n4 + 255) >> 8);
    if (bx < nx4) {
        long i = (long)bx * 256 + threadIdx.x;
        if (i < n4) {
            float4 v = *reinterpret_cast<const float4*>(x + i * 4);
            __half h0, h1, h2, h3, l0, l1, l2, l3;
            splitf16(v.x, h0, l0);
            splitf16(v.y, h1, l1);
            splitf16(v.z, h2, l2);
            splitf16(v.w, h3, l3);
            ushort4 hv = { __half_as_ushort(h0), __half_as_ushort(h1),
                           __half_as_ushort(h2), __half_as_ushort(h3) };
            ushort4 lv = { __half_as_ushort(l0), __half_as_ushort(l1),
                           __half_as_ushort(l2), __half_as_ushort(l3) };
            *reinterpret_cast<ushort4*>(xh + i * 4) = hv;
            *reinterpret_cast<ushort4*>(xl + i * 4) = lv;
        }
        return;
    }
    bx -= nx4;
    int idx = bx * 256 + threadIdx.x;
    const float* W; __half *Wh, *Wl; int M, base;
    constexpr int K = 256;
    if (idx < 65536)       { W = W1; Wh = w1h; Wl = w1l; M = 256; base = idx; }
    else if (idx < 131072) { W = W2; Wh = w2h; Wl = w2l; M = 256; base = idx - 65536; }
    else if (idx < 147456) { W = W3; Wh = w3h; Wl = w3l; M = 64;  base = idx - 131072; }
    else return;
    int k = base / M, n = base - k * M;
    __half h, l;
    splitf16(W[base], h, l);
    Wh[(size_t)n * K + k] = h;
    Wl[(size_t)n * K + k] = l;
}

// ---------------- CSR scans ----------------
// deg[] holds edge-degree; +1 here accounts for the self-loop
__global__ void k_scan1(const int* __restrict__ deg, int* __restrict__ offs,
                        int* __restrict__ bsum, int N) {
    __shared__ int sh[256];
    int i = blockIdx.x * 256 + threadIdx.x;
    int v = (i < N) ? (deg[i] + 1) : 0;
    sh[threadIdx.x] = v;
    __syncthreads();
#pragma unroll
    for (int off = 1; off < 256; off <<= 1) {
        int t = (threadIdx.x >= off) ? sh[threadIdx.x - off] : 0;
        __syncthreads();
        sh[threadIdx.x] += t;
        __syncthreads();
    }
    if (i < N) offs[i] = sh[threadIdx.x] - v;
    if (threadIdx.x == 255) bsum[blockIdx.x] = sh[255];
}

__global__ void k_scan2(int* __restrict__ bsum, int nb) {   // nb <= 256, single block
    __shared__ int sh[256];
    int v = (threadIdx.x < nb) ? bsum[threadIdx.x] : 0;
    sh[threadIdx.x] = v;
    __syncthreads();
#pragma unroll
    for (int off = 1; off < 256; off <<= 1) {
        int t = (threadIdx.x >= off) ? sh[threadIdx.x - off] : 0;
        __syncthreads();
        sh[threadIdx.x] += t;
        __syncthreads();
    }
    if (threadIdx.x < nb) bsum[threadIdx.x] = sh[threadIdx.x] - v;
    if (threadIdx.x == 255) bsum[nb] = sh[255];
}

// finalizes offs AND places each node's self-loop in its segment's last slot
// (edge slots [offs, offs+deg) are filled rank-based by the fused scatter)
__global__ void k_scan3(int* __restrict__ offs, const int* __restrict__ deg,
                        int* __restrict__ csr, const int* __restrict__ bsum,
                        int N, int nb) {
    int i = blockIdx.x * 256 + threadIdx.x;
    if (i < N) {
        int v = offs[i] + bsum[blockIdx.x];
        offs[i] = v;
        csr[v + deg[i]] = i;
    }
    if (i == 0) offs[N] = bsum[nb];
}

// ---------------- fused alpha epilogue (shared by both GEMMs) ----------------
// Block tile = 64 cols = exactly one head (head = c0>>6). Computes
// als/ald[row][head] = sum_col f16(C[row][col]) * a[col] from the SAME rounded
// f16 values stored to C -> bit-identical to a standalone alpha pass.
// ldsf: reused (dead) A-tile LDS, needs 2*2*128 floats = 2KB.
template <typename ACC>
static __device__ __forceinline__ void alpha_epilogue(
        const ACC& acc, float* ldsf, const float* __restrict__ a_src,
        const float* __restrict__ a_dst, float* __restrict__ als,
        float* __restrict__ ald, __half* __restrict__ C,
        int nrows, int M, int H, int r0, int c0,
        int wr, int wc, int quad, int r, int tid) {
    float ps[4][4], pd[4][4];
#pragma unroll
    for (int tr = 0; tr < 4; ++tr)
#pragma unroll
        for (int i = 0; i < 4; ++i) { ps[tr][i] = 0.f; pd[tr][i] = 0.f; }

#pragma unroll
    for (int tr = 0; tr < 4; ++tr)
#pragma unroll
        for (int tc = 0; tc < 2; ++tc) {
            int col = c0 + wc * 32 + tc * 16 + r;
            float av_s = a_src[col], av_d = a_dst[col];
#pragma unroll
            for (int i = 0; i < 4; ++i) {
                int row = r0 + wr * 64 + tr * 16 + quad * 4 + i;
                __half hv = __float2half(acc[tr][tc][i]);
                float vr = __half2float(hv);
                if (row < nrows) C[(size_t)row * M + col] = hv;
                ps[tr][i] = fmaf(vr, av_s, ps[tr][i]);
                pd[tr][i] = fmaf(vr, av_d, pd[tr][i]);
            }
        }
#pragma unroll
    for (int tr = 0; tr < 4; ++tr)
#pragma unroll
        for (int i = 0; i < 4; ++i) {
            float s = ps[tr][i], d2 = pd[tr][i];
#pragma unroll
            for (int off = 1; off < 16; off <<= 1) {
                s  += __shfl_xor(s,  off, 64);
                d2 += __shfl_xor(d2, off, 64);
            }
            if (r == 0) {
                int lrow = wr * 64 + tr * 16 + quad * 4 + i;
                ldsf[(0 * 2 + wc) * 128 + lrow] = s;    // [which][wc][row]
                ldsf[(2 + wc) * 128 + lrow]     = d2;
            }
        }
    __syncthreads();
    int lrow = tid >> 1, which = tid & 1;   // 256 threads -> 128 rows x {src,dst}
    if (lrow < 128) {
        float v = ldsf[(which * 2 + 0) * 128 + lrow] + ldsf[(which * 2 + 1) * 128 + lrow];
        int grow = r0 + lrow;
        if (grow < nrows) {
            float* dst = which ? ald : als;
            dst[(size_t)grow * H + (c0 >> 6)] = v;
        }
    }
}

// ---------------- layer-1 GEMM fused with rank-based edge scatter ----------------
// Grid interleaves 1 gemm block : 2 scatter blocks (gx%3). Scatter is atomic-free:
// csr[offs[dst] + rnk[e]] = src. Independent of the GEMM; kernel boundary orders
// both before k_agg. 3-term f16-split GEMM: C = (Ah+Al)@(Wh+Wl) ~= AhWh+AhWl+AlWh.
// BM=128, BN=64, BK=32; 4 waves 2x2; LDA=40 halves.
__global__ __launch_bounds__(256) void k_g3s(const __half* __restrict__ Ah, const __half* __restrict__ Al,
                                             const __half* __restrict__ Wth, const __half* __restrict__ Wtl,
                                             __half* __restrict__ C, int nrows, int K, int M,
                                             const float* __restrict__ a_src, const float* __restrict__ a_dst,
                                             float* __restrict__ als, float* __restrict__ ald, int H,
                                             int gridRows, int gemmBlocks,
                                             const int* __restrict__ ei, const int* __restrict__ rnk,
                                             const int* __restrict__ offs, int* __restrict__ csr, int E) {
    constexpr int LDA = 40;
    __shared__ __half AH[128 * LDA];
    __shared__ __half AL[128 * LDA];
    __shared__ __half BH[64 * LDA];
    __shared__ __half BL[64 * LDA];

    int gx = blockIdx.x;
    int g = gx / 3, rsel = gx - g * 3;
    if (rsel != 0) {                       // scatter block
        int e = (g * 2 + (rsel - 1)) * 256 + threadIdx.x;
        if (e < E) {
            int dn = ei[E + e];
            csr[offs[dn] + rnk[e]] = ei[e];
        }
        return;
    }
    if (g >= gemmBlocks) return;
    int bxg = g % gridRows, byg = g / gridRows;

    int tid  = threadIdx.x;
    int lane = tid & 63;
    int wave = tid >> 6;
    int wr = wave & 1, wc = wave >> 1;
    int quad = lane >> 4, r = lane & 15;
    int r0 = bxg * 128, c0 = byg * 64;

    f32x4 acc[4][2];
#pragma unroll
    for (int i = 0; i < 4; ++i)
#pragma unroll
        for (int j = 0; j < 2; ++j) acc[i][j] = (f32x4){0.f, 0.f, 0.f, 0.f};

    for (int kc = 0; kc < K; kc += 32) {
#pragma unroll
        for (int it = 0; it < 2; ++it) {
            int row  = (tid >> 2) + it * 64;
            int kseg = (tid & 3) * 8;
            int gr = r0 + row;
            f16x8 vh = (f16x8)(_Float16)0, vl = (f16x8)(_Float16)0;
            if (gr < nrows) {
                vh = *reinterpret_cast<const f16x8*>(Ah + (size_t)gr * K + kc + kseg);
                vl = *reinterpret_cast<const f16x8*>(Al + (size_t)gr * K + kc + kseg);
            }
            *reinterpret_cast<f16x8*>(&AH[row * LDA + kseg]) = vh;
            *reinterpret_cast<f16x8*>(&AL[row * LDA + kseg]) = vl;
        }
        {
            int n    = tid >> 2;
            int kseg = (tid & 3) * 8;
            *reinterpret_cast<f16x8*>(&BH[n * LDA + kseg]) =
                *reinterpret_cast<const f16x8*>(Wth + (size_t)(c0 + n) * K + kc + kseg);
            *reinterpret_cast<f16x8*>(&BL[n * LDA + kseg]) =
                *reinterpret_cast<const f16x8*>(Wtl + (size_t)(c0 + n) * K + kc + kseg);
        }
        __syncthreads();
        int k0 = quad * 8;
        f16x8 ah[4], al[4], bh[2], bl[2];
#pragma unroll
        for (int tr = 0; tr < 4; ++tr) {
            int row = wr * 64 + tr * 16 + r;
            ah[tr] = *reinterpret_cast<const f16x8*>(&AH[row * LDA + k0]);
            al[tr] = *reinterpret_cast<const f16x8*>(&AL[row * LDA + k0]);
        }
#pragma unroll
        for (int tc = 0; tc < 2; ++tc) {
            int col = wc * 32 + tc * 16 + r;
            bh[tc] = *reinterpret_cast<const f16x8*>(&BH[col * LDA + k0]);
            bl[tc] = *reinterpret_cast<const f16x8*>(&BL[col * LDA + k0]);
        }
#pragma unroll
        for (int tr = 0; tr < 4; ++tr)
#pragma unroll
            for (int tc = 0; tc < 2; ++tc) {
                acc[tr][tc] = __builtin_amdgcn_mfma_f32_16x16x32_f16(ah[tr], bh[tc], acc[tr][tc], 0, 0, 0);
                acc[tr][tc] = __builtin_amdgcn_mfma_f32_16x16x32_f16(ah[tr], bl[tc], acc[tr][tc], 0, 0, 0);
                acc[tr][tc] = __builtin_amdgcn_mfma_f32_16x16x32_f16(al[tr], bh[tc], acc[tr][tc], 0, 0, 0);
            }
        __syncthreads();
    }
    alpha_epilogue(acc, reinterpret_cast<float*>(AH), a_src, a_dst, als, ald, C,
                   nrows, M, H, r0, c0, wr, wc, quad, r, tid);
}

// Layers 2/3 (2-term): A is exact f16 -> C = A @ (Wh+Wl). LDS ~20.5 KB.
__global__ __launch_bounds__(256) void k_gemm2(const __half* __restrict__ A,
                                               const __half* __restrict__ Wth, const __half* __restrict__ Wtl,
                                               __half* __restrict__ C, int nrows, int K, int M,
                                               const float* __restrict__ a_src, const float* __restrict__ a_dst,
                                               float* __restrict__ als, float* __restrict__ ald, int H) {
    constexpr int LDA = 40;
    __shared__ __half AS[128 * LDA];
    __shared__ __half BH[64 * LDA];
    __shared__ __half BL[64 * LDA];

    int tid  = threadIdx.x;
    int lane = tid & 63;
    int wave = tid >> 6;
    int wr = wave & 1, wc = wave >> 1;
    int quad = lane >> 4, r = lane & 15;
    int r0 = blockIdx.x * 128, c0 = blockIdx.y * 64;

    f32x4 acc[4][2];
#pragma unroll
    for (int i = 0; i < 4; ++i)
#pragma unroll
        for (int j = 0; j < 2; ++j) acc[i][j] = (f32x4){0.f, 0.f, 0.f, 0.f};

    for (int kc = 0; kc < K; kc += 32) {
#pragma unroll
        for (int it = 0; it < 2; ++it) {
            int row  = (tid >> 2) + it * 64;
            int kseg = (tid & 3) * 8;
            int gr = r0 + row;
            f16x8 v = (f16x8)(_Float16)0;
            if (gr < nrows) v = *reinterpret_cast<const f16x8*>(A + (size_t)gr * K + kc + kseg);
            *reinterpret_cast<f16x8*>(&AS[row * LDA + kseg]) = v;
        }
        {
            int n    = tid >> 2;
            int kseg = (tid & 3) * 8;
            *reinterpret_cast<f16x8*>(&BH[n * LDA + kseg]) =
                *reinterpret_cast<const f16x8*>(Wth + (size_t)(c0 + n) * K + kc + kseg);
            *reinterpret_cast<f16x8*>(&BL[n * LDA + kseg]) =
                *reinterpret_cast<const f16x8*>(Wtl + (size_t)(c0 + n) * K + kc + kseg);
        }
        __syncthreads();
        int k0 = quad * 8;
        f16x8 a[4], bh[2], bl[2];
#pragma unroll
        for (int tr = 0; tr < 4; ++tr) {
            int row = wr * 64 + tr * 16 + r;
            a[tr] = *reinterpret_cast<const f16x8*>(&AS[row * LDA + k0]);
        }
#pragma unroll
        for (int tc = 0; tc < 2; ++tc) {
            int col = wc * 32 + tc * 16 + r;
            bh[tc] = *reinterpret_cast<const f16x8*>(&BH[col * LDA + k0]);
            bl[tc] = *reinterpret_cast<const f16x8*>(&BL[col * LDA + k0]);
        }
#pragma unroll
        for (int tr = 0; tr < 4; ++tr)
#pragma unroll
            for (int tc = 0; tc < 2; ++tc) {
                acc[tr][tc] = __builtin_amdgcn_mfma_f32_16x16x32_f16(a[tr], bh[tc], acc[tr][tc], 0, 0, 0);
                acc[tr][tc] = __builtin_amdgcn_mfma_f32_16x16x32_f16(a[tr], bl[tc], acc[tr][tc], 0, 0, 0);
            }
        __syncthreads();
    }
    alpha_epilogue(acc, reinterpret_cast<float*>(AS), a_src, a_dst, als, ald, C,
                   nrows, M, H, r0, c0, wr, wc, quad, r, tid);
}

// ---------------- GAT aggregation: full-wave lane-parallel weights, EC=16 ----------------
// (Round-2 proven version, verbatim.) Phase A: 16 edges x H heads of weight
// computation mapped onto all 64 lanes. Weights + 32-bit row byte-offsets
// round-trip through wave-private LDS (no barriers; DS ops in-order per wave).
// Phase B: fully-unrolled 16-edge gather (16 independent 8B loads in flight) + FMA.
// Tail chunks clamp padded lanes to the last valid edge (dup loads = L1 hits), w = 0.
template <int CHUNK, bool ELU, typename OT>
__global__ void k_agg(const __half* __restrict__ feat, const int* __restrict__ offs,
                      const int* __restrict__ csr, const float* __restrict__ als,
                      const float* __restrict__ ald, const float* __restrict__ bias,
                      OT* __restrict__ out, int N) {
    constexpr int M  = 64 * CHUNK;              // 256 or 64
    constexpr int H  = (CHUNK == 4) ? 4 : 1;
    constexpr int EC = 16;                      // edges per chunk
    constexpr int SH = (CHUNK == 4) ? 9 : 7;    // log2(M * sizeof(__half))

    __shared__ float    shw[4][2][64];
    __shared__ unsigned sho[4][2][EC];

    int tid  = threadIdx.x;
    int lane = tid & 63;
    int wid  = tid >> 6;
    int node = blockIdx.x * 4 + wid;
    if (node >= N) return;

    int ia = lane & 15;                          // edge slot in phase A
    int ha = (H == 4) ? (lane >> 4) : 0;         // head in phase A (CHUNK=1: groups duplicate)
    int ho = lane >> 4;                          // 16-lane group id == output head (CHUNK=4)

    float adv = ald[(size_t)node * H + ha];

    int beg = offs[node], end = offs[node + 1];
    int d   = end - beg;                         // >= 1 (self-loop)
    int nc  = (d + EC - 1) >> 4;

    const char* fbase = reinterpret_cast<const char*>(feat) + lane * (CHUNK * 2);

    float acc[CHUNK] = {};
    float den = 0.f;

    // prologue: chunk 0 src + logit, chunk 1 src
    int sv = csr[beg + min(ia, min(EC, d) - 1)];
    float xv = als[(size_t)sv * H + ha];
    int sv_n = sv;
    if (nc > 1) {
        int cn = min(EC, d - EC);
        sv_n = csr[beg + EC + min(ia, cn - 1)];
    }

    for (int c = 0; c < nc; ++c) {
        int cnt = min(EC, d - c * EC);

        // ---- phase A: one weight per lane (edge ia, head ha) ----
        float e = xv + adv;
        e = (e > 0.f) ? e : 0.2f * e;
        float w = (ia < cnt) ? __expf(e) : 0.f;
        den += w;
        int b = c & 1;
        shw[wid][b][lane] = w;                   // full-wave ds_write, no predicate
        if (lane < EC) sho[wid][b][lane] = (unsigned)sv << SH;

        // prefetch: logit for chunk c+1 (issued before phase B), src for chunk c+2
        xv = als[(size_t)sv_n * H + ha];
        sv = sv_n;
        if (c + 2 < nc) {
            int cn = min(EC, d - (c + 2) * EC);
            sv_n = csr[beg + (c + 2) * EC + min(ia, cn - 1)];
        }

        // ---- phase B: broadcast-read weights/offsets, 16-deep gather+FMA ----
        const float* wp = &shw[wid][b][ho * EC];
        float4 w0 = *reinterpret_cast<const float4*>(wp);
        float4 w1 = *reinterpret_cast<const float4*>(wp + 4);
        float4 w2 = *reinterpret_cast<const float4*>(wp + 8);
        float4 w3 = *reinterpret_cast<const float4*>(wp + 12);
        const unsigned* op = &sho[wid][b][0];
        uint4 o0 = *reinterpret_cast<const uint4*>(op);
        uint4 o1 = *reinterpret_cast<const uint4*>(op + 4);
        uint4 o2 = *reinterpret_cast<const uint4*>(op + 8);
        uint4 o3 = *reinterpret_cast<const uint4*>(op + 12);
        float    ww[EC] = {w0.x, w0.y, w0.z, w0.w, w1.x, w1.y, w1.z, w1.w,
                           w2.x, w2.y, w2.z, w2.w, w3.x, w3.y, w3.z, w3.w};
        unsigned oo[EC] = {o0.x, o0.y, o0.z, o0.w, o1.x, o1.y, o1.z, o1.w,
                           o2.x, o2.y, o2.z, o2.w, o3.x, o3.y, o3.z, o3.w};
        if constexpr (CHUNK == 4) {
            f16x4 v[EC];
#pragma unroll
            for (int t = 0; t < EC; ++t)
                v[t] = *reinterpret_cast<const f16x4*>(fbase + oo[t]);
#pragma unroll
            for (int t = 0; t < EC; ++t)
#pragma unroll
                for (int j = 0; j < 4; ++j)
                    acc[j] = fmaf((float)v[t][j], ww[t], acc[j]);
        } else {
            __half v[EC];
#pragma unroll
            for (int t = 0; t < EC; ++t)
                v[t] = *reinterpret_cast<const __half*>(fbase + oo[t]);
#pragma unroll
            for (int t = 0; t < EC; ++t)
                acc[0] = fmaf(__half2float(v[t]), ww[t], acc[0]);
        }
    }

    // denominator: reduce within aligned 16-lane groups (group == head for CHUNK=4;
    // CHUNK=1: each group independently computed all edge weights -> full sum)
#pragma unroll
    for (int off = 1; off < EC; off <<= 1) den += __shfl_xor(den, off, 64);
    float inv = 1.f / (den + 1e-16f);

#pragma unroll
    for (int j = 0; j < CHUNK; ++j) {
        int col = lane * CHUNK + j;
        float v = acc[j] * inv + bias[col];
        if (ELU) v = (v > 0.f) ? v : (__expf(v) - 1.f);
        st(&out[(size_t)node * M + col], v);
    }
}

// ---------------- global mean pool: batch sorted -> one block per graph ----------------
static __device__ __forceinline__ int lowerb(const int* __restrict__ a, int n, int v) {
    int lo = 0, hi = n;
    while (lo < hi) { int mid = (lo + hi) >> 1; if (a[mid] < v) lo = mid + 1; else hi = mid; }
    return lo;
}

__global__ void k_pool2(const float* __restrict__ ne, const int* __restrict__ batch,
                        float* __restrict__ gout, int N) {
    int g = blockIdx.x;
    int lo = lowerb(batch, N, g);
    int hi = lowerb(batch, N, g + 1);
    int lane = threadIdx.x & 63, row = threadIdx.x >> 6;
    float s = 0.f;
    for (int i = lo + row; i < hi; i += 4) s += ne[(size_t)i * 64 + lane];
    __shared__ float red[4][64];
    red[row][lane] = s;
    __syncthreads();
    if (row == 0) {
        float v = red[0][lane] + red[1][lane] + red[2][lane] + red[3][lane];
        gout[(size_t)g * 64 + lane] = v / fmaxf((float)(hi - lo), 1.f);
    }
}

extern "C" void kernel_launch(void* const* d_in, const int* in_sizes, int n_in,
                              void* d_out, int out_size, void* d_ws, size_t ws_size,
                              hipStream_t stream) {
    const float* x   = (const float*)d_in[0];
    const int* ei    = (const int*)d_in[1];
    const int* batch = (const int*)d_in[2];
    const float* W1  = (const float*)d_in[3];
    const float* as1 = (const float*)d_in[4];
    const float* ad1 = (const float*)d_in[5];
    const float* b1  = (const float*)d_in[6];
    const float* W2  = (const float*)d_in[7];
    const float* as2 = (const float*)d_in[8];
    const float* ad2 = (const float*)d_in[9];
    const float* b2  = (const float*)d_in[10];
    const float* W3  = (const float*)d_in[11];
    const float* as3 = (const float*)d_in[12];
    const float* ad3 = (const float*)d_in[13];
    const float* b3  = (const float*)d_in[14];

    const int N = in_sizes[2];      // 50000
    const int E = in_sizes[1] / 2;  // 800000
    const int G = 64;
    float* out = (float*)d_out;

    // workspace (~85 MB). act aliases xh (xh/xl dead after layer-1 GEMM).
    char* w = (char*)d_ws;
    auto carve = [&](size_t bytes) { char* p = w; w += (bytes + 255) & ~(size_t)255; return p; };
    __half* feat = (__half*)carve((size_t)N * 256 * 2);   // GEMM output (f16)
    __half* xh   = (__half*)carve((size_t)N * 256 * 2);   // layer-1 A hi; later act
    __half* xl   = (__half*)carve((size_t)N * 256 * 2);   // layer-1 A lo
    __half* act  = xh;                                     // alias: safe after layer-1 GEMM
    float* als   = (float*)carve((size_t)N * 4 * 4);
    float* ald   = (float*)carve((size_t)N * 4 * 4);
    int* deg     = (int*)carve((size_t)N * 4);
    int* offs    = (int*)carve((size_t)(N + 1) * 4);
    int* rnk     = (int*)carve((size_t)E * 4);
    int* csr     = (int*)carve((size_t)(E + N) * 4);
    int nb       = (N + 255) / 256;
    int* bsum    = (int*)carve((size_t)(nb + 1) * 4);
    __half* w1h  = (__half*)carve((size_t)256 * 256 * 2);
    __half* w1l  = (__half*)carve((size_t)256 * 256 * 2);
    __half* w2h  = (__half*)carve((size_t)256 * 256 * 2);
    __half* w2l  = (__half*)carve((size_t)256 * 256 * 2);
    __half* w3h  = (__half*)carve((size_t)256 * 64 * 2);
    __half* w3l  = (__half*)carve((size_t)256 * 64 * 2);

    long n4 = (long)N * 64;            // N*256/4 float4 groups
    int nhist = (E + 255) / 256;
    int nx4   = (int)((n4 + 255) / 256);
    int nwspl = (147456 + 255) / 256;

    // pre-pass: deg memset, then fused {edge hist+rank | x split | W splits}
    hipMemsetAsync(deg, 0, (size_t)N * 4, stream);
    k_pre<<<nhist + nx4 + nwspl, 256, 0, stream>>>(ei, deg, rnk, E, x, xh, xl, n4,
                                                   W1, W2, W3, w1h, w1l, w2h, w2l, w3h, w3l);

    // CSR scans (+ self-loop placement in scan3)
    k_scan1<<<nb, 256, 0, stream>>>(deg, offs, bsum, N);
    k_scan2<<<1, 256, 0, stream>>>(bsum, nb);
    k_scan3<<<nb, 256, 0, stream>>>(offs, deg, csr, bsum, N, nb);

    int gridRows = (N + 127) / 128;
    int gemmBlocks = gridRows * 4;
    int nodeBlocks = (N + 3) / 4;

    // layer 1 GEMM (3-term, alpha fused) interleaved with rank-based edge scatter
    k_g3s<<<3 * gemmBlocks, 256, 0, stream>>>(xh, xl, w1h, w1l, feat, N, 256, 256,
                                              as1, ad1, als, ald, 4,
                                              gridRows, gemmBlocks, ei, rnk, offs, csr, E);
    k_agg<4, true, __half><<<nodeBlocks, 256, 0, stream>>>(feat, offs, csr, als, ald, b1, act, N);
    // layer 2 (A exact f16, 2-term; alpha fused)
    k_gemm2<<<dim3(gridRows, 4), 256, 0, stream>>>(act, w2h, w2l, feat, N, 256, 256,
                                                   as2, ad2, als, ald, 4);
    k_agg<4, true, __half><<<nodeBlocks, 256, 0, stream>>>(feat, offs, csr, als, ald, b2, act, N);
    // layer 3: 256 -> 64, single head, no ELU; fp32 straight to d_out
    k_gemm2<<<dim3(gridRows, 1), 256, 0, stream>>>(act, w3h, w3l, feat, N, 256, 64,
                                                   as3, ad3, als, ald, 1);
    k_agg<1, false, float><<<nodeBlocks, 256, 0, stream>>>(feat, offs, csr, als, ald, b3, out, N);

    // global mean pool
    k_pool2<<<G, 256, 0, stream>>>(out, batch, out + (size_t)N * 64, N);
}

// Round 7
// 475.497 us; speedup vs baseline: 1.2820x; 1.0455x over previous
//
#include <hip/hip_runtime.h>
#include <hip/hip_bf16.h>
#include <hip/hip_fp16.h>

typedef __attribute__((ext_vector_type(8))) _Float16 f16x8;
typedef __attribute__((ext_vector_type(4))) _Float16 f16x4;
typedef __attribute__((ext_vector_type(4))) float f32x4;

static __device__ __forceinline__ void st(float* p, float v)  { *p = v; }
static __device__ __forceinline__ void st(__half* p, float v) { *p = __float2half(v); }

// fp32 -> f16 hi/lo split (residual <= 2^-22 relative)
static __device__ __forceinline__ void splitf16(float v, __half& hi, __half& lo) {
    hi = __float2half(v);
    lo = __float2half(v - __half2float(hi));
}

// ---------------- fused pre-pass: edge histogram(+rank) | x split | W splits ----------------
__global__ void k_pre(const int* __restrict__ ei, int* __restrict__ deg, int* __restrict__ rnk,
                      int E,
                      const float* __restrict__ x, __half* __restrict__ xh,
                      __half* __restrict__ xl, long n4,
                      const float* __restrict__ W1, const float* __restrict__ W2,
                      const float* __restrict__ W3,
                      __half* __restrict__ w1h, __half* __restrict__ w1l,
                      __half* __restrict__ w2h, __half* __restrict__ w2l,
                      __half* __restrict__ w3h, __half* __restrict__ w3l) {
    int bx = blockIdx.x;
    int nhist = (E + 255) >> 8;
    if (bx < nhist) {
        int e = bx * 256 + threadIdx.x;
        if (e < E) rnk[e] = atomicAdd(&deg[ei[E + e]], 1);   // rank within dst segment
        return;
    }
    bx -= nhist;
    int nx4 = (int)((n4 + 255) >> 8);
    if (bx < nx4) {
        long i = (long)bx * 256 + threadIdx.x;
        if (i < n4) {
            float4 v = *reinterpret_cast<const float4*>(x + i * 4);
            __half h0, h1, h2, h3, l0, l1, l2, l3;
            splitf16(v.x, h0, l0);
            splitf16(v.y, h1, l1);
            splitf16(v.z, h2, l2);
            splitf16(v.w, h3, l3);
            ushort4 hv = { __half_as_ushort(h0), __half_as_ushort(h1),
                           __half_as_ushort(h2), __half_as_ushort(h3) };
            ushort4 lv = { __half_as_ushort(l0), __half_as_ushort(l1),
                           __half_as_ushort(l2), __half_as_ushort(l3) };
            *reinterpret_cast<ushort4*>(xh + i * 4) = hv;
            *reinterpret_cast<ushort4*>(xl + i * 4) = lv;
        }
        return;
    }
    bx -= nx4;
    int idx = bx * 256 + threadIdx.x;
    const float* W; __half *Wh, *Wl; int M, base;
    constexpr int K = 256;
    if (idx < 65536)       { W = W1; Wh = w1h; Wl = w1l; M = 256; base = idx; }
    else if (idx < 131072) { W = W2; Wh = w2h; Wl = w2l; M = 256; base = idx - 65536; }
    else if (idx < 147456) { W = W3; Wh = w3h; Wl = w3l; M = 64;  base = idx - 131072; }
    else return;
    int k = base / M, n = base - k * M;
    __half h, l;
    splitf16(W[base], h, l);
    Wh[(size_t)n * K + k] = h;
    Wl[(size_t)n * K + k] = l;
}

// ---------------- CSR scans ----------------
__global__ void k_scan1(const int* __restrict__ deg, int* __restrict__ offs,
                        int* __restrict__ bsum, int N) {
    __shared__ int sh[256];
    int i = blockIdx.x * 256 + threadIdx.x;
    int v = (i < N) ? (deg[i] + 1) : 0;
    sh[threadIdx.x] = v;
    __syncthreads();
#pragma unroll
    for (int off = 1; off < 256; off <<= 1) {
        int t = (threadIdx.x >= off) ? sh[threadIdx.x - off] : 0;
        __syncthreads();
        sh[threadIdx.x] += t;
        __syncthreads();
    }
    if (i < N) offs[i] = sh[threadIdx.x] - v;
    if (threadIdx.x == 255) bsum[blockIdx.x] = sh[255];
}

__global__ void k_scan2(int* __restrict__ bsum, int nb) {   // nb <= 256, single block
    __shared__ int sh[256];
    int v = (threadIdx.x < nb) ? bsum[threadIdx.x] : 0;
    sh[threadIdx.x] = v;
    __syncthreads();
#pragma unroll
    for (int off = 1; off < 256; off <<= 1) {
        int t = (threadIdx.x >= off) ? sh[threadIdx.x - off] : 0;
        __syncthreads();
        sh[threadIdx.x] += t;
        __syncthreads();
    }
    if (threadIdx.x < nb) bsum[threadIdx.x] = sh[threadIdx.x] - v;
    if (threadIdx.x == 255) bsum[nb] = sh[255];
}

// finalizes offs AND places each node's self-loop in its segment's last slot
__global__ void k_scan3(int* __restrict__ offs, const int* __restrict__ deg,
                        int* __restrict__ csr, const int* __restrict__ bsum,
                        int N, int nb) {
    int i = blockIdx.x * 256 + threadIdx.x;
    if (i < N) {
        int v = offs[i] + bsum[blockIdx.x];
        offs[i] = v;
        csr[v + deg[i]] = i;
    }
    if (i == 0) offs[N] = bsum[nb];
}

// ---------------- narrow alpha epilogue (layer-3 GEMM only, BN=64) ----------------
template <typename ACC>
static __device__ __forceinline__ void alpha_epilogue(
        const ACC& acc, float* ldsf, const float* __restrict__ a_src,
        const float* __restrict__ a_dst, float* __restrict__ als,
        float* __restrict__ ald, __half* __restrict__ C,
        int nrows, int M, int H, int r0, int c0,
        int wr, int wc, int quad, int r, int tid) {
    float ps[4][4], pd[4][4];
#pragma unroll
    for (int tr = 0; tr < 4; ++tr)
#pragma unroll
        for (int i = 0; i < 4; ++i) { ps[tr][i] = 0.f; pd[tr][i] = 0.f; }

#pragma unroll
    for (int tr = 0; tr < 4; ++tr)
#pragma unroll
        for (int tc = 0; tc < 2; ++tc) {
            int col = c0 + wc * 32 + tc * 16 + r;
            float av_s = a_src[col], av_d = a_dst[col];
#pragma unroll
            for (int i = 0; i < 4; ++i) {
                int row = r0 + wr * 64 + tr * 16 + quad * 4 + i;
                __half hv = __float2half(acc[tr][tc][i]);
                float vr = __half2float(hv);
                if (row < nrows) C[(size_t)row * M + col] = hv;
                ps[tr][i] = fmaf(vr, av_s, ps[tr][i]);
                pd[tr][i] = fmaf(vr, av_d, pd[tr][i]);
            }
        }
#pragma unroll
    for (int tr = 0; tr < 4; ++tr)
#pragma unroll
        for (int i = 0; i < 4; ++i) {
            float s = ps[tr][i], d2 = pd[tr][i];
#pragma unroll
            for (int off = 1; off < 16; off <<= 1) {
                s  += __shfl_xor(s,  off, 64);
                d2 += __shfl_xor(d2, off, 64);
            }
            if (r == 0) {
                int lrow = wr * 64 + tr * 16 + quad * 4 + i;
                ldsf[(0 * 2 + wc) * 128 + lrow] = s;    // [which][wc][row]
                ldsf[(2 + wc) * 128 + lrow]     = d2;
            }
        }
    __syncthreads();
    int lrow = tid >> 1, which = tid & 1;   // 256 threads -> 128 rows x {src,dst}
    if (lrow < 128) {
        float v = ldsf[(which * 2 + 0) * 128 + lrow] + ldsf[(which * 2 + 1) * 128 + lrow];
        int grow = r0 + lrow;
        if (grow < nrows) {
            float* dst = which ? ald : als;
            dst[(size_t)grow * H + (c0 >> 6)] = v;
        }
    }
}

// ---------------- wide alpha epilogue (BN=128): each wave owns one 64-col head ----------------
// Pure registers + shfl; no LDS, no barrier. Head = (c0>>6) + wc.
template <typename ACC>
static __device__ __forceinline__ void alpha_epilogue_w(
        const ACC& acc, const float* __restrict__ a_src, const float* __restrict__ a_dst,
        float* __restrict__ als, float* __restrict__ ald, __half* __restrict__ C,
        int nrows, int M, int H, int r0, int c0, int wr, int wc, int quad, int r) {
    int head = (c0 >> 6) + wc;
    float ps[4][4], pd[4][4];
#pragma unroll
    for (int tr = 0; tr < 4; ++tr)
#pragma unroll
        for (int i = 0; i < 4; ++i) { ps[tr][i] = 0.f; pd[tr][i] = 0.f; }

#pragma unroll
    for (int tr = 0; tr < 4; ++tr)
#pragma unroll
        for (int tc = 0; tc < 4; ++tc) {
            int col = c0 + wc * 64 + tc * 16 + r;
            float av_s = a_src[col], av_d = a_dst[col];
#pragma unroll
            for (int i = 0; i < 4; ++i) {
                int row = r0 + wr * 64 + tr * 16 + quad * 4 + i;
                __half hv = __float2half(acc[tr][tc][i]);
                float vr = __half2float(hv);
                if (row < nrows) C[(size_t)row * M + col] = hv;
                ps[tr][i] = fmaf(vr, av_s, ps[tr][i]);
                pd[tr][i] = fmaf(vr, av_d, pd[tr][i]);
            }
        }
#pragma unroll
    for (int tr = 0; tr < 4; ++tr)
#pragma unroll
        for (int i = 0; i < 4; ++i) {
            float s = ps[tr][i], d2 = pd[tr][i];
#pragma unroll
            for (int off = 1; off < 16; off <<= 1) {
                s  += __shfl_xor(s,  off, 64);
                d2 += __shfl_xor(d2, off, 64);
            }
            if (r == 0) {
                int row = r0 + wr * 64 + tr * 16 + quad * 4 + i;
                if (row < nrows) {
                    als[(size_t)row * H + head] = s;
                    ald[(size_t)row * H + head] = d2;
                }
            }
        }
}

// ---------------- layer-1 GEMM (wide 128x128) fused with rank-based edge scatter ----------------
// Grid interleaves 1 gemm block : 4 scatter blocks (gx%5). Scatter is atomic-free:
// csr[offs[dst] + rnk[e]] = src. 3-term f16-split GEMM: C=(Ah+Al)@(Wh+Wl)~=AhWh+AhWl+AlWh.
// BM=128, BN=128, BK=32; 4 waves 2x2 (each wave: 64 rows x 64 cols = one head).
__global__ __launch_bounds__(256) void k_g3s(const __half* __restrict__ Ah, const __half* __restrict__ Al,
                                             const __half* __restrict__ Wth, const __half* __restrict__ Wtl,
                                             __half* __restrict__ C, int nrows, int K, int M,
                                             const float* __restrict__ a_src, const float* __restrict__ a_dst,
                                             float* __restrict__ als, float* __restrict__ ald, int H,
                                             int gridRows,
                                             const int* __restrict__ ei, const int* __restrict__ rnk,
                                             const int* __restrict__ offs, int* __restrict__ csr, int E) {
    constexpr int LDA = 40;
    __shared__ __half AH[128 * LDA];
    __shared__ __half AL[128 * LDA];
    __shared__ __half BH[128 * LDA];
    __shared__ __half BL[128 * LDA];

    int gx = blockIdx.x;
    int g = gx / 5, rsel = gx - g * 5;
    if (rsel != 0) {                       // scatter block
        int e = (g * 4 + (rsel - 1)) * 256 + threadIdx.x;
        if (e < E) {
            int dn = ei[E + e];
            csr[offs[dn] + rnk[e]] = ei[e];
        }
        return;
    }
    int bxg = g % gridRows, byg = g / gridRows;

    int tid  = threadIdx.x;
    int lane = tid & 63;
    int wave = tid >> 6;
    int wr = wave & 1, wc = wave >> 1;
    int quad = lane >> 4, r = lane & 15;
    int r0 = bxg * 128, c0 = byg * 128;

    f32x4 acc[4][4];
#pragma unroll
    for (int i = 0; i < 4; ++i)
#pragma unroll
        for (int j = 0; j < 4; ++j) acc[i][j] = (f32x4){0.f, 0.f, 0.f, 0.f};

    for (int kc = 0; kc < K; kc += 32) {
#pragma unroll
        for (int it = 0; it < 2; ++it) {
            int row  = (tid >> 2) + it * 64;
            int kseg = (tid & 3) * 8;
            int gr = r0 + row;
            f16x8 vh = (f16x8)(_Float16)0, vl = (f16x8)(_Float16)0;
            if (gr < nrows) {
                vh = *reinterpret_cast<const f16x8*>(Ah + (size_t)gr * K + kc + kseg);
                vl = *reinterpret_cast<const f16x8*>(Al + (size_t)gr * K + kc + kseg);
            }
            *reinterpret_cast<f16x8*>(&AH[row * LDA + kseg]) = vh;
            *reinterpret_cast<f16x8*>(&AL[row * LDA + kseg]) = vl;
        }
#pragma unroll
        for (int it = 0; it < 2; ++it) {
            int n    = (tid >> 2) + it * 64;
            int kseg = (tid & 3) * 8;
            *reinterpret_cast<f16x8*>(&BH[n * LDA + kseg]) =
                *reinterpret_cast<const f16x8*>(Wth + (size_t)(c0 + n) * K + kc + kseg);
            *reinterpret_cast<f16x8*>(&BL[n * LDA + kseg]) =
                *reinterpret_cast<const f16x8*>(Wtl + (size_t)(c0 + n) * K + kc + kseg);
        }
        __syncthreads();
        int k0 = quad * 8;
        f16x8 ah[4], al[4], bh[4], bl[4];
#pragma unroll
        for (int tr = 0; tr < 4; ++tr) {
            int row = wr * 64 + tr * 16 + r;
            ah[tr] = *reinterpret_cast<const f16x8*>(&AH[row * LDA + k0]);
            al[tr] = *reinterpret_cast<const f16x8*>(&AL[row * LDA + k0]);
        }
#pragma unroll
        for (int tc = 0; tc < 4; ++tc) {
            int col = wc * 64 + tc * 16 + r;
            bh[tc] = *reinterpret_cast<const f16x8*>(&BH[col * LDA + k0]);
            bl[tc] = *reinterpret_cast<const f16x8*>(&BL[col * LDA + k0]);
        }
#pragma unroll
        for (int tr = 0; tr < 4; ++tr)
#pragma unroll
            for (int tc = 0; tc < 4; ++tc) {
                acc[tr][tc] = __builtin_amdgcn_mfma_f32_16x16x32_f16(ah[tr], bh[tc], acc[tr][tc], 0, 0, 0);
                acc[tr][tc] = __builtin_amdgcn_mfma_f32_16x16x32_f16(ah[tr], bl[tc], acc[tr][tc], 0, 0, 0);
                acc[tr][tc] = __builtin_amdgcn_mfma_f32_16x16x32_f16(al[tr], bh[tc], acc[tr][tc], 0, 0, 0);
            }
        __syncthreads();
    }
    alpha_epilogue_w(acc, a_src, a_dst, als, ald, C, nrows, M, H, r0, c0, wr, wc, quad, r);
}

// Layer-2 GEMM (wide 128x128, 2-term): A exact f16 -> C = A @ (Wh+Wl). LDS ~30.7 KB.
__global__ __launch_bounds__(256) void k_gemm2w(const __half* __restrict__ A,
                                                const __half* __restrict__ Wth, const __half* __restrict__ Wtl,
                                                __half* __restrict__ C, int nrows, int K, int M,
                                                const float* __restrict__ a_src, const float* __restrict__ a_dst,
                                                float* __restrict__ als, float* __restrict__ ald, int H) {
    constexpr int LDA = 40;
    __shared__ __half AS[128 * LDA];
    __shared__ __half BH[128 * LDA];
    __shared__ __half BL[128 * LDA];

    int tid  = threadIdx.x;
    int lane = tid & 63;
    int wave = tid >> 6;
    int wr = wave & 1, wc = wave >> 1;
    int quad = lane >> 4, r = lane & 15;
    int r0 = blockIdx.x * 128, c0 = blockIdx.y * 128;

    f32x4 acc[4][4];
#pragma unroll
    for (int i = 0; i < 4; ++i)
#pragma unroll
        for (int j = 0; j < 4; ++j) acc[i][j] = (f32x4){0.f, 0.f, 0.f, 0.f};

    for (int kc = 0; kc < K; kc += 32) {
#pragma unroll
        for (int it = 0; it < 2; ++it) {
            int row  = (tid >> 2) + it * 64;
            int kseg = (tid & 3) * 8;
            int gr = r0 + row;
            f16x8 v = (f16x8)(_Float16)0;
            if (gr < nrows) v = *reinterpret_cast<const f16x8*>(A + (size_t)gr * K + kc + kseg);
            *reinterpret_cast<f16x8*>(&AS[row * LDA + kseg]) = v;
        }
#pragma unroll
        for (int it = 0; it < 2; ++it) {
            int n    = (tid >> 2) + it * 64;
            int kseg = (tid & 3) * 8;
            *reinterpret_cast<f16x8*>(&BH[n * LDA + kseg]) =
                *reinterpret_cast<const f16x8*>(Wth + (size_t)(c0 + n) * K + kc + kseg);
            *reinterpret_cast<f16x8*>(&BL[n * LDA + kseg]) =
                *reinterpret_cast<const f16x8*>(Wtl + (size_t)(c0 + n) * K + kc + kseg);
        }
        __syncthreads();
        int k0 = quad * 8;
        f16x8 a[4], bh[4], bl[4];
#pragma unroll
        for (int tr = 0; tr < 4; ++tr) {
            int row = wr * 64 + tr * 16 + r;
            a[tr] = *reinterpret_cast<const f16x8*>(&AS[row * LDA + k0]);
        }
#pragma unroll
        for (int tc = 0; tc < 4; ++tc) {
            int col = wc * 64 + tc * 16 + r;
            bh[tc] = *reinterpret_cast<const f16x8*>(&BH[col * LDA + k0]);
            bl[tc] = *reinterpret_cast<const f16x8*>(&BL[col * LDA + k0]);
        }
#pragma unroll
        for (int tr = 0; tr < 4; ++tr)
#pragma unroll
            for (int tc = 0; tc < 4; ++tc) {
                acc[tr][tc] = __builtin_amdgcn_mfma_f32_16x16x32_f16(a[tr], bh[tc], acc[tr][tc], 0, 0, 0);
                acc[tr][tc] = __builtin_amdgcn_mfma_f32_16x16x32_f16(a[tr], bl[tc], acc[tr][tc], 0, 0, 0);
            }
        __syncthreads();
    }
    alpha_epilogue_w(acc, a_src, a_dst, als, ald, C, nrows, M, H, r0, c0, wr, wc, quad, r);
}

// Layer-3 GEMM (narrow 128x64, 2-term, proven): M=64, single head.
__global__ __launch_bounds__(256) void k_gemm2(const __half* __restrict__ A,
                                               const __half* __restrict__ Wth, const __half* __restrict__ Wtl,
                                               __half* __restrict__ C, int nrows, int K, int M,
                                               const float* __restrict__ a_src, const float* __restrict__ a_dst,
                                               float* __restrict__ als, float* __restrict__ ald, int H) {
    constexpr int LDA = 40;
    __shared__ __half AS[128 * LDA];
    __shared__ __half BH[64 * LDA];
    __shared__ __half BL[64 * LDA];

    int tid  = threadIdx.x;
    int lane = tid & 63;
    int wave = tid >> 6;
    int wr = wave & 1, wc = wave >> 1;
    int quad = lane >> 4, r = lane & 15;
    int r0 = blockIdx.x * 128, c0 = blockIdx.y * 64;

    f32x4 acc[4][2];
#pragma unroll
    for (int i = 0; i < 4; ++i)
#pragma unroll
        for (int j = 0; j < 2; ++j) acc[i][j] = (f32x4){0.f, 0.f, 0.f, 0.f};

    for (int kc = 0; kc < K; kc += 32) {
#pragma unroll
        for (int it = 0; it < 2; ++it) {
            int row  = (tid >> 2) + it * 64;
            int kseg = (tid & 3) * 8;
            int gr = r0 + row;
            f16x8 v = (f16x8)(_Float16)0;
            if (gr < nrows) v = *reinterpret_cast<const f16x8*>(A + (size_t)gr * K + kc + kseg);
            *reinterpret_cast<f16x8*>(&AS[row * LDA + kseg]) = v;
        }
        {
            int n    = tid >> 2;
            int kseg = (tid & 3) * 8;
            *reinterpret_cast<f16x8*>(&BH[n * LDA + kseg]) =
                *reinterpret_cast<const f16x8*>(Wth + (size_t)(c0 + n) * K + kc + kseg);
            *reinterpret_cast<f16x8*>(&BL[n * LDA + kseg]) =
                *reinterpret_cast<const f16x8*>(Wtl + (size_t)(c0 + n) * K + kc + kseg);
        }
        __syncthreads();
        int k0 = quad * 8;
        f16x8 a[4], bh[2], bl[2];
#pragma unroll
        for (int tr = 0; tr < 4; ++tr) {
            int row = wr * 64 + tr * 16 + r;
            a[tr] = *reinterpret_cast<const f16x8*>(&AS[row * LDA + k0]);
        }
#pragma unroll
        for (int tc = 0; tc < 2; ++tc) {
            int col = wc * 32 + tc * 16 + r;
            bh[tc] = *reinterpret_cast<const f16x8*>(&BH[col * LDA + k0]);
            bl[tc] = *reinterpret_cast<const f16x8*>(&BL[col * LDA + k0]);
        }
#pragma unroll
        for (int tr = 0; tr < 4; ++tr)
#pragma unroll
            for (int tc = 0; tc < 2; ++tc) {
                acc[tr][tc] = __builtin_amdgcn_mfma_f32_16x16x32_f16(a[tr], bh[tc], acc[tr][tc], 0, 0, 0);
                acc[tr][tc] = __builtin_amdgcn_mfma_f32_16x16x32_f16(a[tr], bl[tc], acc[tr][tc], 0, 0, 0);
            }
        __syncthreads();
    }
    alpha_epilogue(acc, reinterpret_cast<float*>(AS), a_src, a_dst, als, ald, C,
                   nrows, M, H, r0, c0, wr, wc, quad, r, tid);
}

// ---------------- GAT aggregation: full-wave lane-parallel weights, EC=16 (proven) ----------------
template <int CHUNK, bool ELU, typename OT>
__global__ void k_agg(const __half* __restrict__ feat, const int* __restrict__ offs,
                      const int* __restrict__ csr, const float* __restrict__ als,
                      const float* __restrict__ ald, const float* __restrict__ bias,
                      OT* __restrict__ out, int N) {
    constexpr int M  = 64 * CHUNK;              // 256 or 64
    constexpr int H  = (CHUNK == 4) ? 4 : 1;
    constexpr int EC = 16;                      // edges per chunk
    constexpr int SH = (CHUNK == 4) ? 9 : 7;    // log2(M * sizeof(__half))

    __shared__ float    shw[4][2][64];
    __shared__ unsigned sho[4][2][EC];

    int tid  = threadIdx.x;
    int lane = tid & 63;
    int wid  = tid >> 6;
    int node = blockIdx.x * 4 + wid;
    if (node >= N) return;

    int ia = lane & 15;                          // edge slot in phase A
    int ha = (H == 4) ? (lane >> 4) : 0;         // head in phase A (CHUNK=1: groups duplicate)
    int ho = lane >> 4;                          // 16-lane group id == output head (CHUNK=4)

    float adv = ald[(size_t)node * H + ha];

    int beg = offs[node], end = offs[node + 1];
    int d   = end - beg;                         // >= 1 (self-loop)
    int nc  = (d + EC - 1) >> 4;

    const char* fbase = reinterpret_cast<const char*>(feat) + lane * (CHUNK * 2);

    float acc[CHUNK] = {};
    float den = 0.f;

    // prologue: chunk 0 src + logit, chunk 1 src
    int sv = csr[beg + min(ia, min(EC, d) - 1)];
    float xv = als[(size_t)sv * H + ha];
    int sv_n = sv;
    if (nc > 1) {
        int cn = min(EC, d - EC);
        sv_n = csr[beg + EC + min(ia, cn - 1)];
    }

    for (int c = 0; c < nc; ++c) {
        int cnt = min(EC, d - c * EC);

        // ---- phase A: one weight per lane (edge ia, head ha) ----
        float e = xv + adv;
        e = (e > 0.f) ? e : 0.2f * e;
        float w = (ia < cnt) ? __expf(e) : 0.f;
        den += w;
        int b = c & 1;
        shw[wid][b][lane] = w;                   // full-wave ds_write, no predicate
        if (lane < EC) sho[wid][b][lane] = (unsigned)sv << SH;

        // prefetch: logit for chunk c+1 (issued before phase B), src for chunk c+2
        xv = als[(size_t)sv_n * H + ha];
        sv = sv_n;
        if (c + 2 < nc) {
            int cn = min(EC, d - (c + 2) * EC);
            sv_n = csr[beg + (c + 2) * EC + min(ia, cn - 1)];
        }

        // ---- phase B: broadcast-read weights/offsets, 16-deep gather+FMA ----
        const float* wp = &shw[wid][b][ho * EC];
        float4 w0 = *reinterpret_cast<const float4*>(wp);
        float4 w1 = *reinterpret_cast<const float4*>(wp + 4);
        float4 w2 = *reinterpret_cast<const float4*>(wp + 8);
        float4 w3 = *reinterpret_cast<const float4*>(wp + 12);
        const unsigned* op = &sho[wid][b][0];
        uint4 o0 = *reinterpret_cast<const uint4*>(op);
        uint4 o1 = *reinterpret_cast<const uint4*>(op + 4);
        uint4 o2 = *reinterpret_cast<const uint4*>(op + 8);
        uint4 o3 = *reinterpret_cast<const uint4*>(op + 12);
        float    ww[EC] = {w0.x, w0.y, w0.z, w0.w, w1.x, w1.y, w1.z, w1.w,
                           w2.x, w2.y, w2.z, w2.w, w3.x, w3.y, w3.z, w3.w};
        unsigned oo[EC] = {o0.x, o0.y, o0.z, o0.w, o1.x, o1.y, o1.z, o1.w,
                           o2.x, o2.y, o2.z, o2.w, o3.x, o3.y, o3.z, o3.w};
        if constexpr (CHUNK == 4) {
            f16x4 v[EC];
#pragma unroll
            for (int t = 0; t < EC; ++t)
                v[t] = *reinterpret_cast<const f16x4*>(fbase + oo[t]);
#pragma unroll
            for (int t = 0; t < EC; ++t)
#pragma unroll
                for (int j = 0; j < 4; ++j)
                    acc[j] = fmaf((float)v[t][j], ww[t], acc[j]);
        } else {
            __half v[EC];
#pragma unroll
            for (int t = 0; t < EC; ++t)
                v[t] = *reinterpret_cast<const __half*>(fbase + oo[t]);
#pragma unroll
            for (int t = 0; t < EC; ++t)
                acc[0] = fmaf(__half2float(v[t]), ww[t], acc[0]);
        }
    }

    // denominator: reduce within aligned 16-lane groups
#pragma unroll
    for (int off = 1; off < EC; off <<= 1) den += __shfl_xor(den, off, 64);
    float inv = 1.f / (den + 1e-16f);

#pragma unroll
    for (int j = 0; j < CHUNK; ++j) {
        int col = lane * CHUNK + j;
        float v = acc[j] * inv + bias[col];
        if (ELU) v = (v > 0.f) ? v : (__expf(v) - 1.f);
        st(&out[(size_t)node * M + col], v);
    }
}

// ---------------- global mean pool: batch sorted -> one block per graph ----------------
static __device__ __forceinline__ int lowerb(const int* __restrict__ a, int n, int v) {
    int lo = 0, hi = n;
    while (lo < hi) { int mid = (lo + hi) >> 1; if (a[mid] < v) lo = mid + 1; else hi = mid; }
    return lo;
}

__global__ void k_pool2(const float* __restrict__ ne, const int* __restrict__ batch,
                        float* __restrict__ gout, int N) {
    int g = blockIdx.x;
    int lo = lowerb(batch, N, g);
    int hi = lowerb(batch, N, g + 1);
    int lane = threadIdx.x & 63, row = threadIdx.x >> 6;
    float s = 0.f;
    for (int i = lo + row; i < hi; i += 4) s += ne[(size_t)i * 64 + lane];
    __shared__ float red[4][64];
    red[row][lane] = s;
    __syncthreads();
    if (row == 0) {
        float v = red[0][lane] + red[1][lane] + red[2][lane] + red[3][lane];
        gout[(size_t)g * 64 + lane] = v / fmaxf((float)(hi - lo), 1.f);
    }
}

extern "C" void kernel_launch(void* const* d_in, const int* in_sizes, int n_in,
                              void* d_out, int out_size, void* d_ws, size_t ws_size,
                              hipStream_t stream) {
    const float* x   = (const float*)d_in[0];
    const int* ei    = (const int*)d_in[1];
    const int* batch = (const int*)d_in[2];
    const float* W1  = (const float*)d_in[3];
    const float* as1 = (const float*)d_in[4];
    const float* ad1 = (const float*)d_in[5];
    const float* b1  = (const float*)d_in[6];
    const float* W2  = (const float*)d_in[7];
    const float* as2 = (const float*)d_in[8];
    const float* ad2 = (const float*)d_in[9];
    const float* b2  = (const float*)d_in[10];
    const float* W3  = (const float*)d_in[11];
    const float* as3 = (const float*)d_in[12];
    const float* ad3 = (const float*)d_in[13];
    const float* b3  = (const float*)d_in[14];

    const int N = in_sizes[2];      // 50000
    const int E = in_sizes[1] / 2;  // 800000
    const int G = 64;
    float* out = (float*)d_out;

    // workspace (~85 MB). act aliases xh (xh/xl dead after layer-1 GEMM).
    char* w = (char*)d_ws;
    auto carve = [&](size_t bytes) { char* p = w; w += (bytes + 255) & ~(size_t)255; return p; };
    __half* feat = (__half*)carve((size_t)N * 256 * 2);   // GEMM output (f16)
    __half* xh   = (__half*)carve((size_t)N * 256 * 2);   // layer-1 A hi; later act
    __half* xl   = (__half*)carve((size_t)N * 256 * 2);   // layer-1 A lo
    __half* act  = xh;                                     // alias: safe after layer-1 GEMM
    float* als   = (float*)carve((size_t)N * 4 * 4);
    float* ald   = (float*)carve((size_t)N * 4 * 4);
    int* deg     = (int*)carve((size_t)N * 4);
    int* offs    = (int*)carve((size_t)(N + 1) * 4);
    int* rnk     = (int*)carve((size_t)E * 4);
    int* csr     = (int*)carve((size_t)(E + N) * 4);
    int nb       = (N + 255) / 256;
    int* bsum    = (int*)carve((size_t)(nb + 1) * 4);
    __half* w1h  = (__half*)carve((size_t)256 * 256 * 2);
    __half* w1l  = (__half*)carve((size_t)256 * 256 * 2);
    __half* w2h  = (__half*)carve((size_t)256 * 256 * 2);
    __half* w2l  = (__half*)carve((size_t)256 * 256 * 2);
    __half* w3h  = (__half*)carve((size_t)256 * 64 * 2);
    __half* w3l  = (__half*)carve((size_t)256 * 64 * 2);

    long n4 = (long)N * 64;            // N*256/4 float4 groups
    int nhist = (E + 255) / 256;
    int nx4   = (int)((n4 + 255) / 256);
    int nwspl = (147456 + 255) / 256;

    // pre-pass: deg memset, then fused {edge hist+rank | x split | W splits}
    hipMemsetAsync(deg, 0, (size_t)N * 4, stream);
    k_pre<<<nhist + nx4 + nwspl, 256, 0, stream>>>(ei, deg, rnk, E, x, xh, xl, n4,
                                                   W1, W2, W3, w1h, w1l, w2h, w2l, w3h, w3l);

    // CSR scans (+ self-loop placement in scan3)
    k_scan1<<<nb, 256, 0, stream>>>(deg, offs, bsum, N);
    k_scan2<<<1, 256, 0, stream>>>(bsum, nb);
    k_scan3<<<nb, 256, 0, stream>>>(offs, deg, csr, bsum, N, nb);

    int gridRows = (N + 127) / 128;          // 391
    int gemmBlocks = gridRows * 2;           // BN=128 -> 2 col blocks for M=256
    int nodeBlocks = (N + 3) / 4;

    // layer 1 GEMM (wide 3-term, alpha fused) interleaved 1:4 with rank-based edge scatter
    k_g3s<<<5 * gemmBlocks, 256, 0, stream>>>(xh, xl, w1h, w1l, feat, N, 256, 256,
                                              as1, ad1, als, ald, 4,
                                              gridRows, ei, rnk, offs, csr, E);
    k_agg<4, true, __half><<<nodeBlocks, 256, 0, stream>>>(feat, offs, csr, als, ald, b1, act, N);
    // layer 2 (wide 2-term, alpha fused)
    k_gemm2w<<<dim3(gridRows, 2), 256, 0, stream>>>(act, w2h, w2l, feat, N, 256, 256,
                                                    as2, ad2, als, ald, 4);
    k_agg<4, true, __half><<<nodeBlocks, 256, 0, stream>>>(feat, offs, csr, als, ald, b2, act, N);
    // layer 3: 256 -> 64, single head, no ELU; fp32 straight to d_out (narrow proven kernel)
    k_gemm2<<<dim3(gridRows, 1), 256, 0, stream>>>(act, w3h, w3l, feat, N, 256, 64,
                                                   as3, ad3, als, ald, 1);
    k_agg<1, false, float><<<nodeBlocks, 256, 0, stream>>>(feat, offs, csr, als, ald, b3, out, N);

    // global mean pool
    k_pool2<<<G, 256, 0, stream>>>(out, batch, out + (size_t)N * 64, N);
}

// Round 8
// 468.966 us; speedup vs baseline: 1.2998x; 1.0139x over previous
//
#include <hip/hip_runtime.h>
#include <hip/hip_bf16.h>
#include <hip/hip_fp16.h>

typedef __attribute__((ext_vector_type(8))) _Float16 f16x8;
typedef __attribute__((ext_vector_type(4))) _Float16 f16x4;
typedef __attribute__((ext_vector_type(4))) float f32x4;

static __device__ __forceinline__ void st(float* p, float v)  { *p = v; }
static __device__ __forceinline__ void st(__half* p, float v) { *p = __float2half(v); }

// fp32 -> f16 hi/lo split (residual <= 2^-22 relative)
static __device__ __forceinline__ void splitf16(float v, __half& hi, __half& lo) {
    hi = __float2half(v);
    lo = __float2half(v - __half2float(hi));
}

// async global->LDS 16B (gfx950 global_load_lds_dwordx4):
// per-lane global address; hardware writes wave-uniform LDS base + lane*16.
static __device__ __forceinline__ void gload16(const void* g, void* l) {
    __builtin_amdgcn_global_load_lds(
        (const __attribute__((address_space(1))) unsigned int*)g,
        (__attribute__((address_space(3))) unsigned int*)l, 16, 0, 0);
}

// stage a 128x32-half tile (8KB, linear [128][32]) from src rows row0..row0+127.
// 8 chunks of 1KB: chunk = i*4 + wave; lane covers row = chunk*16 + lane/4,
// kseg = (lane&3)*8 halves. LDS base per chunk is wave-uniform.
static __device__ __forceinline__ void stage_tile(const __half* __restrict__ src,
                                                  int row0, int kc, int K,
                                                  __half* lds, int wave, int lane) {
#pragma unroll
    for (int i = 0; i < 2; ++i) {
        int chunk = i * 4 + wave;
        int row   = chunk * 16 + (lane >> 2);
        int kseg  = (lane & 3) * 8;
        gload16(src + (size_t)(row0 + row) * K + kc + kseg, lds + chunk * 512);
    }
}

// ---------------- fused pre-pass: edge histogram(+rank) | x split | W splits ----------------
__global__ void k_pre(const int* __restrict__ ei, int* __restrict__ deg, int* __restrict__ rnk,
                      int E,
                      const float* __restrict__ x, __half* __restrict__ xh,
                      __half* __restrict__ xl, long n4,
                      const float* __restrict__ W1, const float* __restrict__ W2,
                      const float* __restrict__ W3,
                      __half* __restrict__ w1h, __half* __restrict__ w1l,
                      __half* __restrict__ w2h, __half* __restrict__ w2l,
                      __half* __restrict__ w3h, __half* __restrict__ w3l) {
    int bx = blockIdx.x;
    int nhist = (E + 255) >> 8;
    if (bx < nhist) {
        int e = bx * 256 + threadIdx.x;
        if (e < E) rnk[e] = atomicAdd(&deg[ei[E + e]], 1);   // rank within dst segment
        return;
    }
    bx -= nhist;
    int nx4 = (int)((n4 + 255) >> 8);
    if (bx < nx4) {
        long i = (long)bx * 256 + threadIdx.x;
        if (i < n4) {
            float4 v = *reinterpret_cast<const float4*>(x + i * 4);
            __half h0, h1, h2, h3, l0, l1, l2, l3;
            splitf16(v.x, h0, l0);
            splitf16(v.y, h1, l1);
            splitf16(v.z, h2, l2);
            splitf16(v.w, h3, l3);
            ushort4 hv = { __half_as_ushort(h0), __half_as_ushort(h1),
                           __half_as_ushort(h2), __half_as_ushort(h3) };
            ushort4 lv = { __half_as_ushort(l0), __half_as_ushort(l1),
                           __half_as_ushort(l2), __half_as_ushort(l3) };
            *reinterpret_cast<ushort4*>(xh + i * 4) = hv;
            *reinterpret_cast<ushort4*>(xl + i * 4) = lv;
        }
        return;
    }
    bx -= nx4;
    int idx = bx * 256 + threadIdx.x;
    const float* W; __half *Wh, *Wl; int M, base;
    constexpr int K = 256;
    if (idx < 65536)       { W = W1; Wh = w1h; Wl = w1l; M = 256; base = idx; }
    else if (idx < 131072) { W = W2; Wh = w2h; Wl = w2l; M = 256; base = idx - 65536; }
    else if (idx < 147456) { W = W3; Wh = w3h; Wl = w3l; M = 64;  base = idx - 131072; }
    else return;
    int k = base / M, n = base - k * M;
    __half h, l;
    splitf16(W[base], h, l);
    Wh[(size_t)n * K + k] = h;
    Wl[(size_t)n * K + k] = l;
}

// ---------------- CSR scans ----------------
__global__ void k_scan1(const int* __restrict__ deg, int* __restrict__ offs,
                        int* __restrict__ bsum, int N) {
    __shared__ int sh[256];
    int i = blockIdx.x * 256 + threadIdx.x;
    int v = (i < N) ? (deg[i] + 1) : 0;
    sh[threadIdx.x] = v;
    __syncthreads();
#pragma unroll
    for (int off = 1; off < 256; off <<= 1) {
        int t = (threadIdx.x >= off) ? sh[threadIdx.x - off] : 0;
        __syncthreads();
        sh[threadIdx.x] += t;
        __syncthreads();
    }
    if (i < N) offs[i] = sh[threadIdx.x] - v;
    if (threadIdx.x == 255) bsum[blockIdx.x] = sh[255];
}

__global__ void k_scan2(int* __restrict__ bsum, int nb) {   // nb <= 256, single block
    __shared__ int sh[256];
    int v = (threadIdx.x < nb) ? bsum[threadIdx.x] : 0;
    sh[threadIdx.x] = v;
    __syncthreads();
#pragma unroll
    for (int off = 1; off < 256; off <<= 1) {
        int t = (threadIdx.x >= off) ? sh[threadIdx.x - off] : 0;
        __syncthreads();
        sh[threadIdx.x] += t;
        __syncthreads();
    }
    if (threadIdx.x < nb) bsum[threadIdx.x] = sh[threadIdx.x] - v;
    if (threadIdx.x == 255) bsum[nb] = sh[255];
}

// finalizes offs AND places each node's self-loop in its segment's last slot
__global__ void k_scan3(int* __restrict__ offs, const int* __restrict__ deg,
                        int* __restrict__ csr, const int* __restrict__ bsum,
                        int N, int nb) {
    int i = blockIdx.x * 256 + threadIdx.x;
    if (i < N) {
        int v = offs[i] + bsum[blockIdx.x];
        offs[i] = v;
        csr[v + deg[i]] = i;
    }
    if (i == 0) offs[N] = bsum[nb];
}

// ---------------- narrow alpha epilogue (layer-3 GEMM only, BN=64) ----------------
template <typename ACC>
static __device__ __forceinline__ void alpha_epilogue(
        const ACC& acc, float* ldsf, const float* __restrict__ a_src,
        const float* __restrict__ a_dst, float* __restrict__ als,
        float* __restrict__ ald, __half* __restrict__ C,
        int nrows, int M, int H, int r0, int c0,
        int wr, int wc, int quad, int r, int tid) {
    float ps[4][4], pd[4][4];
#pragma unroll
    for (int tr = 0; tr < 4; ++tr)
#pragma unroll
        for (int i = 0; i < 4; ++i) { ps[tr][i] = 0.f; pd[tr][i] = 0.f; }

#pragma unroll
    for (int tr = 0; tr < 4; ++tr)
#pragma unroll
        for (int tc = 0; tc < 2; ++tc) {
            int col = c0 + wc * 32 + tc * 16 + r;
            float av_s = a_src[col], av_d = a_dst[col];
#pragma unroll
            for (int i = 0; i < 4; ++i) {
                int row = r0 + wr * 64 + tr * 16 + quad * 4 + i;
                __half hv = __float2half(acc[tr][tc][i]);
                float vr = __half2float(hv);
                if (row < nrows) C[(size_t)row * M + col] = hv;
                ps[tr][i] = fmaf(vr, av_s, ps[tr][i]);
                pd[tr][i] = fmaf(vr, av_d, pd[tr][i]);
            }
        }
#pragma unroll
    for (int tr = 0; tr < 4; ++tr)
#pragma unroll
        for (int i = 0; i < 4; ++i) {
            float s = ps[tr][i], d2 = pd[tr][i];
#pragma unroll
            for (int off = 1; off < 16; off <<= 1) {
                s  += __shfl_xor(s,  off, 64);
                d2 += __shfl_xor(d2, off, 64);
            }
            if (r == 0) {
                int lrow = wr * 64 + tr * 16 + quad * 4 + i;
                ldsf[(0 * 2 + wc) * 128 + lrow] = s;    // [which][wc][row]
                ldsf[(2 + wc) * 128 + lrow]     = d2;
            }
        }
    __syncthreads();
    int lrow = tid >> 1, which = tid & 1;   // 256 threads -> 128 rows x {src,dst}
    if (lrow < 128) {
        float v = ldsf[(which * 2 + 0) * 128 + lrow] + ldsf[(which * 2 + 1) * 128 + lrow];
        int grow = r0 + lrow;
        if (grow < nrows) {
            float* dst = which ? ald : als;
            dst[(size_t)grow * H + (c0 >> 6)] = v;
        }
    }
}

// ---------------- wide alpha epilogue (BN=128): each wave owns one 64-col head ----------------
template <typename ACC>
static __device__ __forceinline__ void alpha_epilogue_w(
        const ACC& acc, const float* __restrict__ a_src, const float* __restrict__ a_dst,
        float* __restrict__ als, float* __restrict__ ald, __half* __restrict__ C,
        int nrows, int M, int H, int r0, int c0, int wr, int wc, int quad, int r) {
    int head = (c0 >> 6) + wc;
    float ps[4][4], pd[4][4];
#pragma unroll
    for (int tr = 0; tr < 4; ++tr)
#pragma unroll
        for (int i = 0; i < 4; ++i) { ps[tr][i] = 0.f; pd[tr][i] = 0.f; }

#pragma unroll
    for (int tr = 0; tr < 4; ++tr)
#pragma unroll
        for (int tc = 0; tc < 4; ++tc) {
            int col = c0 + wc * 64 + tc * 16 + r;
            float av_s = a_src[col], av_d = a_dst[col];
#pragma unroll
            for (int i = 0; i < 4; ++i) {
                int row = r0 + wr * 64 + tr * 16 + quad * 4 + i;
                __half hv = __float2half(acc[tr][tc][i]);
                float vr = __half2float(hv);
                if (row < nrows) C[(size_t)row * M + col] = hv;
                ps[tr][i] = fmaf(vr, av_s, ps[tr][i]);
                pd[tr][i] = fmaf(vr, av_d, pd[tr][i]);
            }
        }
#pragma unroll
    for (int tr = 0; tr < 4; ++tr)
#pragma unroll
        for (int i = 0; i < 4; ++i) {
            float s = ps[tr][i], d2 = pd[tr][i];
#pragma unroll
            for (int off = 1; off < 16; off <<= 1) {
                s  += __shfl_xor(s,  off, 64);
                d2 += __shfl_xor(d2, off, 64);
            }
            if (r == 0) {
                int row = r0 + wr * 64 + tr * 16 + quad * 4 + i;
                if (row < nrows) {
                    als[(size_t)row * H + head] = s;
                    ald[(size_t)row * H + head] = d2;
                }
            }
        }
}

// ---------------- layer-1 GEMM (wide 128x128, async-staged) + rank-based edge scatter ----------------
// BM=128, BN=128, BK=32; linear LDS [128][32] staged via global_load_lds (no pad:
// HW writes wave-uniform base + lane*16). Tail-block rows >= nrows load garbage from
// the adjacent workspace buffer; those rows never store (guarded) -> bit-identical.
__global__ __launch_bounds__(256) void k_g3s(const __half* __restrict__ Ah, const __half* __restrict__ Al,
                                             const __half* __restrict__ Wth, const __half* __restrict__ Wtl,
                                             __half* __restrict__ C, int nrows, int K, int M,
                                             const float* __restrict__ a_src, const float* __restrict__ a_dst,
                                             float* __restrict__ als, float* __restrict__ ald, int H,
                                             int gridRows,
                                             const int* __restrict__ ei, const int* __restrict__ rnk,
                                             const int* __restrict__ offs, int* __restrict__ csr, int E) {
    constexpr int LDA = 32;
    __shared__ __half AH[128 * LDA];
    __shared__ __half AL[128 * LDA];
    __shared__ __half BH[128 * LDA];
    __shared__ __half BL[128 * LDA];

    int gx = blockIdx.x;
    int g = gx / 5, rsel = gx - g * 5;
    if (rsel != 0) {                       // scatter block
        int e = (g * 4 + (rsel - 1)) * 256 + threadIdx.x;
        if (e < E) {
            int dn = ei[E + e];
            csr[offs[dn] + rnk[e]] = ei[e];
        }
        return;
    }
    int bxg = g % gridRows, byg = g / gridRows;

    int tid  = threadIdx.x;
    int lane = tid & 63;
    int wave = tid >> 6;
    int wr = wave & 1, wc = wave >> 1;
    int quad = lane >> 4, r = lane & 15;
    int r0 = bxg * 128, c0 = byg * 128;

    f32x4 acc[4][4];
#pragma unroll
    for (int i = 0; i < 4; ++i)
#pragma unroll
        for (int j = 0; j < 4; ++j) acc[i][j] = (f32x4){0.f, 0.f, 0.f, 0.f};

    for (int kc = 0; kc < K; kc += 32) {
        stage_tile(Ah,  r0, kc, K, AH, wave, lane);
        stage_tile(Al,  r0, kc, K, AL, wave, lane);
        stage_tile(Wth, c0, kc, K, BH, wave, lane);
        stage_tile(Wtl, c0, kc, K, BL, wave, lane);
        __syncthreads();
        int k0 = quad * 8;
        f16x8 ah[4], al[4], bh[4], bl[4];
#pragma unroll
        for (int tr = 0; tr < 4; ++tr) {
            int row = wr * 64 + tr * 16 + r;
            ah[tr] = *reinterpret_cast<const f16x8*>(&AH[row * LDA + k0]);
            al[tr] = *reinterpret_cast<const f16x8*>(&AL[row * LDA + k0]);
        }
#pragma unroll
        for (int tc = 0; tc < 4; ++tc) {
            int col = wc * 64 + tc * 16 + r;
            bh[tc] = *reinterpret_cast<const f16x8*>(&BH[col * LDA + k0]);
            bl[tc] = *reinterpret_cast<const f16x8*>(&BL[col * LDA + k0]);
        }
#pragma unroll
        for (int tr = 0; tr < 4; ++tr)
#pragma unroll
            for (int tc = 0; tc < 4; ++tc) {
                acc[tr][tc] = __builtin_amdgcn_mfma_f32_16x16x32_f16(ah[tr], bh[tc], acc[tr][tc], 0, 0, 0);
                acc[tr][tc] = __builtin_amdgcn_mfma_f32_16x16x32_f16(ah[tr], bl[tc], acc[tr][tc], 0, 0, 0);
                acc[tr][tc] = __builtin_amdgcn_mfma_f32_16x16x32_f16(al[tr], bh[tc], acc[tr][tc], 0, 0, 0);
            }
        __syncthreads();
    }
    alpha_epilogue_w(acc, a_src, a_dst, als, ald, C, nrows, M, H, r0, c0, wr, wc, quad, r);
}

// Layer-2 GEMM (wide 128x128, 2-term, async-staged): C = A @ (Wh+Wl). LDS 24 KB.
__global__ __launch_bounds__(256) void k_gemm2w(const __half* __restrict__ A,
                                                const __half* __restrict__ Wth, const __half* __restrict__ Wtl,
                                                __half* __restrict__ C, int nrows, int K, int M,
                                                const float* __restrict__ a_src, const float* __restrict__ a_dst,
                                                float* __restrict__ als, float* __restrict__ ald, int H) {
    constexpr int LDA = 32;
    __shared__ __half AS[128 * LDA];
    __shared__ __half BH[128 * LDA];
    __shared__ __half BL[128 * LDA];

    int tid  = threadIdx.x;
    int lane = tid & 63;
    int wave = tid >> 6;
    int wr = wave & 1, wc = wave >> 1;
    int quad = lane >> 4, r = lane & 15;
    int r0 = blockIdx.x * 128, c0 = blockIdx.y * 128;

    f32x4 acc[4][4];
#pragma unroll
    for (int i = 0; i < 4; ++i)
#pragma unroll
        for (int j = 0; j < 4; ++j) acc[i][j] = (f32x4){0.f, 0.f, 0.f, 0.f};

    for (int kc = 0; kc < K; kc += 32) {
        stage_tile(A,   r0, kc, K, AS, wave, lane);
        stage_tile(Wth, c0, kc, K, BH, wave, lane);
        stage_tile(Wtl, c0, kc, K, BL, wave, lane);
        __syncthreads();
        int k0 = quad * 8;
        f16x8 a[4], bh[4], bl[4];
#pragma unroll
        for (int tr = 0; tr < 4; ++tr) {
            int row = wr * 64 + tr * 16 + r;
            a[tr] = *reinterpret_cast<const f16x8*>(&AS[row * LDA + k0]);
        }
#pragma unroll
        for (int tc = 0; tc < 4; ++tc) {
            int col = wc * 64 + tc * 16 + r;
            bh[tc] = *reinterpret_cast<const f16x8*>(&BH[col * LDA + k0]);
            bl[tc] = *reinterpret_cast<const f16x8*>(&BL[col * LDA + k0]);
        }
#pragma unroll
        for (int tr = 0; tr < 4; ++tr)
#pragma unroll
            for (int tc = 0; tc < 4; ++tc) {
                acc[tr][tc] = __builtin_amdgcn_mfma_f32_16x16x32_f16(a[tr], bh[tc], acc[tr][tc], 0, 0, 0);
                acc[tr][tc] = __builtin_amdgcn_mfma_f32_16x16x32_f16(a[tr], bl[tc], acc[tr][tc], 0, 0, 0);
            }
        __syncthreads();
    }
    alpha_epilogue_w(acc, a_src, a_dst, als, ald, C, nrows, M, H, r0, c0, wr, wc, quad, r);
}

// Layer-3 GEMM (narrow 128x64, 2-term, proven): M=64, single head.
__global__ __launch_bounds__(256) void k_gemm2(const __half* __restrict__ A,
                                               const __half* __restrict__ Wth, const __half* __restrict__ Wtl,
                                               __half* __restrict__ C, int nrows, int K, int M,
                                               const float* __restrict__ a_src, const float* __restrict__ a_dst,
                                               float* __restrict__ als, float* __restrict__ ald, int H) {
    constexpr int LDA = 40;
    __shared__ __half AS[128 * LDA];
    __shared__ __half BH[64 * LDA];
    __shared__ __half BL[64 * LDA];

    int tid  = threadIdx.x;
    int lane = tid & 63;
    int wave = tid >> 6;
    int wr = wave & 1, wc = wave >> 1;
    int quad = lane >> 4, r = lane & 15;
    int r0 = blockIdx.x * 128, c0 = blockIdx.y * 64;

    f32x4 acc[4][2];
#pragma unroll
    for (int i = 0; i < 4; ++i)
#pragma unroll
        for (int j = 0; j < 2; ++j) acc[i][j] = (f32x4){0.f, 0.f, 0.f, 0.f};

    for (int kc = 0; kc < K; kc += 32) {
#pragma unroll
        for (int it = 0; it < 2; ++it) {
            int row  = (tid >> 2) + it * 64;
            int kseg = (tid & 3) * 8;
            int gr = r0 + row;
            f16x8 v = (f16x8)(_Float16)0;
            if (gr < nrows) v = *reinterpret_cast<const f16x8*>(A + (size_t)gr * K + kc + kseg);
            *reinterpret_cast<f16x8*>(&AS[row * LDA + kseg]) = v;
        }
        {
            int n    = tid >> 2;
            int kseg = (tid & 3) * 8;
            *reinterpret_cast<f16x8*>(&BH[n * LDA + kseg]) =
                *reinterpret_cast<const f16x8*>(Wth + (size_t)(c0 + n) * K + kc + kseg);
            *reinterpret_cast<f16x8*>(&BL[n * LDA + kseg]) =
                *reinterpret_cast<const f16x8*>(Wtl + (size_t)(c0 + n) * K + kc + kseg);
        }
        __syncthreads();
        int k0 = quad * 8;
        f16x8 a[4], bh[2], bl[2];
#pragma unroll
        for (int tr = 0; tr < 4; ++tr) {
            int row = wr * 64 + tr * 16 + r;
            a[tr] = *reinterpret_cast<const f16x8*>(&AS[row * LDA + k0]);
        }
#pragma unroll
        for (int tc = 0; tc < 2; ++tc) {
            int col = wc * 32 + tc * 16 + r;
            bh[tc] = *reinterpret_cast<const f16x8*>(&BH[col * LDA + k0]);
            bl[tc] = *reinterpret_cast<const f16x8*>(&BL[col * LDA + k0]);
        }
#pragma unroll
        for (int tr = 0; tr < 4; ++tr)
#pragma unroll
            for (int tc = 0; tc < 2; ++tc) {
                acc[tr][tc] = __builtin_amdgcn_mfma_f32_16x16x32_f16(a[tr], bh[tc], acc[tr][tc], 0, 0, 0);
                acc[tr][tc] = __builtin_amdgcn_mfma_f32_16x16x32_f16(a[tr], bl[tc], acc[tr][tc], 0, 0, 0);
            }
        __syncthreads();
    }
    alpha_epilogue(acc, reinterpret_cast<float*>(AS), a_src, a_dst, als, ald, C,
                   nrows, M, H, r0, c0, wr, wc, quad, r, tid);
}

// ---------------- GAT aggregation: full-wave lane-parallel weights, EC=16 (proven) ----------------
template <int CHUNK, bool ELU, typename OT>
__global__ void k_agg(const __half* __restrict__ feat, const int* __restrict__ offs,
                      const int* __restrict__ csr, const float* __restrict__ als,
                      const float* __restrict__ ald, const float* __restrict__ bias,
                      OT* __restrict__ out, int N) {
    constexpr int M  = 64 * CHUNK;              // 256 or 64
    constexpr int H  = (CHUNK == 4) ? 4 : 1;
    constexpr int EC = 16;                      // edges per chunk
    constexpr int SH = (CHUNK == 4) ? 9 : 7;    // log2(M * sizeof(__half))

    __shared__ float    shw[4][2][64];
    __shared__ unsigned sho[4][2][EC];

    int tid  = threadIdx.x;
    int lane = tid & 63;
    int wid  = tid >> 6;
    int node = blockIdx.x * 4 + wid;
    if (node >= N) return;

    int ia = lane & 15;                          // edge slot in phase A
    int ha = (H == 4) ? (lane >> 4) : 0;         // head in phase A (CHUNK=1: groups duplicate)
    int ho = lane >> 4;                          // 16-lane group id == output head (CHUNK=4)

    float adv = ald[(size_t)node * H + ha];

    int beg = offs[node], end = offs[node + 1];
    int d   = end - beg;                         // >= 1 (self-loop)
    int nc  = (d + EC - 1) >> 4;

    const char* fbase = reinterpret_cast<const char*>(feat) + lane * (CHUNK * 2);

    float acc[CHUNK] = {};
    float den = 0.f;

    // prologue: chunk 0 src + logit, chunk 1 src
    int sv = csr[beg + min(ia, min(EC, d) - 1)];
    float xv = als[(size_t)sv * H + ha];
    int sv_n = sv;
    if (nc > 1) {
        int cn = min(EC, d - EC);
        sv_n = csr[beg + EC + min(ia, cn - 1)];
    }

    for (int c = 0; c < nc; ++c) {
        int cnt = min(EC, d - c * EC);

        // ---- phase A: one weight per lane (edge ia, head ha) ----
        float e = xv + adv;
        e = (e > 0.f) ? e : 0.2f * e;
        float w = (ia < cnt) ? __expf(e) : 0.f;
        den += w;
        int b = c & 1;
        shw[wid][b][lane] = w;                   // full-wave ds_write, no predicate
        if (lane < EC) sho[wid][b][lane] = (unsigned)sv << SH;

        // prefetch: logit for chunk c+1 (issued before phase B), src for chunk c+2
        xv = als[(size_t)sv_n * H + ha];
        sv = sv_n;
        if (c + 2 < nc) {
            int cn = min(EC, d - (c + 2) * EC);
            sv_n = csr[beg + (c + 2) * EC + min(ia, cn - 1)];
        }

        // ---- phase B: broadcast-read weights/offsets, 16-deep gather+FMA ----
        const float* wp = &shw[wid][b][ho * EC];
        float4 w0 = *reinterpret_cast<const float4*>(wp);
        float4 w1 = *reinterpret_cast<const float4*>(wp + 4);
        float4 w2 = *reinterpret_cast<const float4*>(wp + 8);
        float4 w3 = *reinterpret_cast<const float4*>(wp + 12);
        const unsigned* op = &sho[wid][b][0];
        uint4 o0 = *reinterpret_cast<const uint4*>(op);
        uint4 o1 = *reinterpret_cast<const uint4*>(op + 4);
        uint4 o2 = *reinterpret_cast<const uint4*>(op + 8);
        uint4 o3 = *reinterpret_cast<const uint4*>(op + 12);
        float    ww[EC] = {w0.x, w0.y, w0.z, w0.w, w1.x, w1.y, w1.z, w1.w,
                           w2.x, w2.y, w2.z, w2.w, w3.x, w3.y, w3.z, w3.w};
        unsigned oo[EC] = {o0.x, o0.y, o0.z, o0.w, o1.x, o1.y, o1.z, o1.w,
                           o2.x, o2.y, o2.z, o2.w, o3.x, o3.y, o3.z, o3.w};
        if constexpr (CHUNK == 4) {
            f16x4 v[EC];
#pragma unroll
            for (int t = 0; t < EC; ++t)
                v[t] = *reinterpret_cast<const f16x4*>(fbase + oo[t]);
#pragma unroll
            for (int t = 0; t < EC; ++t)
#pragma unroll
                for (int j = 0; j < 4; ++j)
                    acc[j] = fmaf((float)v[t][j], ww[t], acc[j]);
        } else {
            __half v[EC];
#pragma unroll
            for (int t = 0; t < EC; ++t)
                v[t] = *reinterpret_cast<const __half*>(fbase + oo[t]);
#pragma unroll
            for (int t = 0; t < EC; ++t)
                acc[0] = fmaf(__half2float(v[t]), ww[t], acc[0]);
        }
    }

    // denominator: reduce within aligned 16-lane groups
#pragma unroll
    for (int off = 1; off < EC; off <<= 1) den += __shfl_xor(den, off, 64);
    float inv = 1.f / (den + 1e-16f);

#pragma unroll
    for (int j = 0; j < CHUNK; ++j) {
        int col = lane * CHUNK + j;
        float v = acc[j] * inv + bias[col];
        if (ELU) v = (v > 0.f) ? v : (__expf(v) - 1.f);
        st(&out[(size_t)node * M + col], v);
    }
}

// ---------------- global mean pool: batch sorted -> one block per graph ----------------
static __device__ __forceinline__ int lowerb(const int* __restrict__ a, int n, int v) {
    int lo = 0, hi = n;
    while (lo < hi) { int mid = (lo + hi) >> 1; if (a[mid] < v) lo = mid + 1; else hi = mid; }
    return lo;
}

__global__ void k_pool2(const float* __restrict__ ne, const int* __restrict__ batch,
                        float* __restrict__ gout, int N) {
    int g = blockIdx.x;
    int lo = lowerb(batch, N, g);
    int hi = lowerb(batch, N, g + 1);
    int lane = threadIdx.x & 63, row = threadIdx.x >> 6;
    float s = 0.f;
    for (int i = lo + row; i < hi; i += 4) s += ne[(size_t)i * 64 + lane];
    __shared__ float red[4][64];
    red[row][lane] = s;
    __syncthreads();
    if (row == 0) {
        float v = red[0][lane] + red[1][lane] + red[2][lane] + red[3][lane];
        gout[(size_t)g * 64 + lane] = v / fmaxf((float)(hi - lo), 1.f);
    }
}

extern "C" void kernel_launch(void* const* d_in, const int* in_sizes, int n_in,
                              void* d_out, int out_size, void* d_ws, size_t ws_size,
                              hipStream_t stream) {
    const float* x   = (const float*)d_in[0];
    const int* ei    = (const int*)d_in[1];
    const int* batch = (const int*)d_in[2];
    const float* W1  = (const float*)d_in[3];
    const float* as1 = (const float*)d_in[4];
    const float* ad1 = (const float*)d_in[5];
    const float* b1  = (const float*)d_in[6];
    const float* W2  = (const float*)d_in[7];
    const float* as2 = (const float*)d_in[8];
    const float* ad2 = (const float*)d_in[9];
    const float* b2  = (const float*)d_in[10];
    const float* W3  = (const float*)d_in[11];
    const float* as3 = (const float*)d_in[12];
    const float* ad3 = (const float*)d_in[13];
    const float* b3  = (const float*)d_in[14];

    const int N = in_sizes[2];      // 50000
    const int E = in_sizes[1] / 2;  // 800000
    const int G = 64;
    float* out = (float*)d_out;

    // workspace (~85 MB). act aliases xh (xh/xl dead after layer-1 GEMM).
    char* w = (char*)d_ws;
    auto carve = [&](size_t bytes) { char* p = w; w += (bytes + 255) & ~(size_t)255; return p; };
    __half* feat = (__half*)carve((size_t)N * 256 * 2);   // GEMM output (f16)
    __half* xh   = (__half*)carve((size_t)N * 256 * 2);   // layer-1 A hi; later act
    __half* xl   = (__half*)carve((size_t)N * 256 * 2);   // layer-1 A lo
    __half* act  = xh;                                     // alias: safe after layer-1 GEMM
    float* als   = (float*)carve((size_t)N * 4 * 4);
    float* ald   = (float*)carve((size_t)N * 4 * 4);
    int* deg     = (int*)carve((size_t)N * 4);
    int* offs    = (int*)carve((size_t)(N + 1) * 4);
    int* rnk     = (int*)carve((size_t)E * 4);
    int* csr     = (int*)carve((size_t)(E + N) * 4);
    int nb       = (N + 255) / 256;
    int* bsum    = (int*)carve((size_t)(nb + 1) * 4);
    __half* w1h  = (__half*)carve((size_t)256 * 256 * 2);
    __half* w1l  = (__half*)carve((size_t)256 * 256 * 2);
    __half* w2h  = (__half*)carve((size_t)256 * 256 * 2);
    __half* w2l  = (__half*)carve((size_t)256 * 256 * 2);
    __half* w3h  = (__half*)carve((size_t)256 * 64 * 2);
    __half* w3l  = (__half*)carve((size_t)256 * 64 * 2);

    long n4 = (long)N * 64;            // N*256/4 float4 groups
    int nhist = (E + 255) / 256;
    int nx4   = (int)((n4 + 255) / 256);
    int nwspl = (147456 + 255) / 256;

    // pre-pass: deg memset, then fused {edge hist+rank | x split | W splits}
    hipMemsetAsync(deg, 0, (size_t)N * 4, stream);
    k_pre<<<nhist + nx4 + nwspl, 256, 0, stream>>>(ei, deg, rnk, E, x, xh, xl, n4,
                                                   W1, W2, W3, w1h, w1l, w2h, w2l, w3h, w3l);

    // CSR scans (+ self-loop placement in scan3)
    k_scan1<<<nb, 256, 0, stream>>>(deg, offs, bsum, N);
    k_scan2<<<1, 256, 0, stream>>>(bsum, nb);
    k_scan3<<<nb, 256, 0, stream>>>(offs, deg, csr, bsum, N, nb);

    int gridRows = (N + 127) / 128;          // 391
    int gemmBlocks = gridRows * 2;           // BN=128 -> 2 col blocks for M=256
    int nodeBlocks = (N + 3) / 4;

    // layer 1 GEMM (wide 3-term, async-staged, alpha fused) interleaved 1:4 with edge scatter
    k_g3s<<<5 * gemmBlocks, 256, 0, stream>>>(xh, xl, w1h, w1l, feat, N, 256, 256,
                                              as1, ad1, als, ald, 4,
                                              gridRows, ei, rnk, offs, csr, E);
    k_agg<4, true, __half><<<nodeBlocks, 256, 0, stream>>>(feat, offs, csr, als, ald, b1, act, N);
    // layer 2 (wide 2-term, async-staged, alpha fused)
    k_gemm2w<<<dim3(gridRows, 2), 256, 0, stream>>>(act, w2h, w2l, feat, N, 256, 256,
                                                    as2, ad2, als, ald, 4);
    k_agg<4, true, __half><<<nodeBlocks, 256, 0, stream>>>(feat, offs, csr, als, ald, b2, act, N);
    // layer 3: 256 -> 64, single head, no ELU; fp32 straight to d_out (narrow proven kernel)
    k_gemm2<<<dim3(gridRows, 1), 256, 0, stream>>>(act, w3h, w3l, feat, N, 256, 64,
                                                   as3, ad3, als, ald, 1);
    k_agg<1, false, float><<<nodeBlocks, 256, 0, stream>>>(feat, offs, csr, als, ald, b3, out, N);

    // global mean pool
    k_pool2<<<G, 256, 0, stream>>>(out, batch, out + (size_t)N * 64, N);
}